// Round 2
// baseline (182.187 us; speedup 1.0000x reference)
//
#include <hip/hip_runtime.h>

// Problem dims (fixed)
#define B_  2
#define S_  1024
#define D_  1024
#define H_  16
#define DH_ 64

typedef __attribute__((ext_vector_type(8))) short bf16x8;
typedef __attribute__((ext_vector_type(4))) float f32x4;

__device__ __forceinline__ unsigned short f2bf(float f) {
  unsigned int u = __float_as_uint(f);
  u += 0x7fff + ((u >> 16) & 1);   // round-to-nearest-even
  return (unsigned short)(u >> 16);
}

__device__ __forceinline__ void gload_lds16(const void* g, void* l) {
  __builtin_amdgcn_global_load_lds(
      (const __attribute__((address_space(1))) unsigned int*)g,
      (__attribute__((address_space(3))) unsigned int*)l, 16, 0, 0);
}

// ---------------------------------------------------------------------------
// Kernel 1: fp32 -> bf16 convert for x, W_qkv, W_out
// ---------------------------------------------------------------------------
__global__ __launch_bounds__(256)
void cvt_kernel(const float4* __restrict__ x, const float4* __restrict__ wq,
                const float4* __restrict__ wo, unsigned short* __restrict__ xb,
                unsigned short* __restrict__ wqb, unsigned short* __restrict__ wob) {
  constexpr int n1 = (B_*S_*D_) / 4;       // 524288
  constexpr int n2 = (3*D_*D_) / 4;        // 786432
  constexpr int n3 = (D_*D_) / 4;          // 262144
  for (int i = blockIdx.x*blockDim.x + threadIdx.x; i < n1+n2+n3;
       i += gridDim.x*blockDim.x) {
    const float4* src; unsigned short* dst; int off;
    if (i < n1)          { src = x;  dst = xb;  off = i; }
    else if (i < n1+n2)  { src = wq; dst = wqb; off = i - n1; }
    else                 { src = wo; dst = wob; off = i - n1 - n2; }
    float4 v = src[off];
    ushort4 r;
    r.x = f2bf(v.x); r.y = f2bf(v.y); r.z = f2bf(v.z); r.w = f2bf(v.w);
    *(ushort4*)&dst[off*4] = r;
  }
}

// ---------------------------------------------------------------------------
// GEMM C = A @ Bw^T, A:[M,K] bf16 row-major, Bw:[N,K] bf16 row-major.
// m97 structure: 128x128 tile, BK=32, global_load_lds(16B), 4 waves (2x2),
// each wave 64x64 = 4x4 frags of 16x16x32 MFMA.
// EPI=0: store fp32 C.  EPI=1: scatter to Q/K [B,H,S,DH] and Vt [B,H,DH,S] bf16.
// ---------------------------------------------------------------------------
template<int M, int N, int K, int EPI>
__global__ __launch_bounds__(256)
void gemm_bt(const unsigned short* __restrict__ A, const unsigned short* __restrict__ Bw,
             float* __restrict__ C, unsigned short* __restrict__ Qb,
             unsigned short* __restrict__ Kb, unsigned short* __restrict__ Vtb) {
  constexpr int NBN = N / 128;
  __shared__ unsigned short As[128*32];
  __shared__ unsigned short Bs[128*32];
  const int tid = threadIdx.x;
  const int bid = blockIdx.x;
  const int mb = bid / NBN, nb = bid % NBN;
  const int wid = tid >> 6, lane = tid & 63;
  const int wr = wid >> 1, wc = wid & 1;
  const int lg = lane >> 4, lr = lane & 15;

  f32x4 acc[4][4] = {};

  const int mrow = mb*128, nrow = nb*128;
  const int srow = tid >> 2;       // 0..63
  const int scol = (tid & 3) * 8;  // 0,8,16,24

  for (int k0 = 0; k0 < K; k0 += 32) {
    #pragma unroll
    for (int h = 0; h < 2; ++h) {
      gload_lds16(A  + (size_t)(mrow + h*64 + srow)*K + k0 + scol, &As[(h*256 + tid)*8]);
      gload_lds16(Bw + (size_t)(nrow + h*64 + srow)*K + k0 + scol, &Bs[(h*256 + tid)*8]);
    }
    __syncthreads();   // emits vmcnt(0) drain before barrier
    bf16x8 af[4], bfr[4];
    #pragma unroll
    for (int t = 0; t < 4; ++t) {
      af[t]  = *(const bf16x8*)&As[(wr*64 + t*16 + lr)*32 + lg*8];
      bfr[t] = *(const bf16x8*)&Bs[(wc*64 + t*16 + lr)*32 + lg*8];
    }
    #pragma unroll
    for (int mt = 0; mt < 4; ++mt)
      #pragma unroll
      for (int nt = 0; nt < 4; ++nt)
        acc[mt][nt] = __builtin_amdgcn_mfma_f32_16x16x32_bf16(af[mt], bfr[nt], acc[mt][nt], 0, 0, 0);
    __syncthreads();
  }

  // Epilogue. C/D layout: row = lg*4 + i, col = lr  (verified m89/m91).
  #pragma unroll
  for (int mt = 0; mt < 4; ++mt) {
    const int m0 = mrow + wr*64 + mt*16 + lg*4;
    #pragma unroll
    for (int nt = 0; nt < 4; ++nt) {
      const int n = nrow + wc*64 + nt*16 + lr;
      f32x4 v = acc[mt][nt];
      if constexpr (EPI == 0) {
        #pragma unroll
        for (int i = 0; i < 4; ++i) C[(size_t)(m0 + i)*N + n] = v[i];
      } else {
        const int t3 = n >> 10, rem = n & 1023;
        const int hh = rem >> 6, dh = rem & 63;
        const int b = m0 >> 10, s0 = m0 & 1023;  // all 4 i share b (128 | 1024)
        if (t3 == 2) {
          // V transposed: Vt[b,h,dh,s]; 4 consecutive s -> one 8B store
          ushort4 pk;
          pk.x = f2bf(v[0]); pk.y = f2bf(v[1]); pk.z = f2bf(v[2]); pk.w = f2bf(v[3]);
          *(ushort4*)&Vtb[(size_t)((b*H_ + hh)*DH_ + dh)*S_ + s0] = pk;
        } else {
          unsigned short* dst = (t3 == 0) ? Qb : Kb;  // [b,h,s,dh]
          #pragma unroll
          for (int i = 0; i < 4; ++i)
            dst[(size_t)((b*H_ + hh)*S_ + s0 + i)*DH_ + dh] = f2bf(v[i]);
        }
      }
    }
  }
}

// ---------------------------------------------------------------------------
// Flash attention v2. Grid: B*H*(S/64)=512 blocks, 512 thr = 8 waves:
//   qw = wid&3  -> 16-q-row sub-tile within the 64-row q-tile
//   kvh = wid>>2 -> KV half (keys [kvh*512, kvh*512+512))
// KVBLK=64: 4 score frags/iter, 16 MFMA/iter, 8 iters. V preloaded before
// softmax (latency off critical path). End: kvh=1 waves publish (m,l,o) via
// LDS; kvh=0 waves merge (flash-decoding combine) and store.
// ---------------------------------------------------------------------------
__global__ __launch_bounds__(512, 4)
void attn_kernel(const unsigned short* __restrict__ Qb, const unsigned short* __restrict__ Kb,
                 const unsigned short* __restrict__ Vtb, unsigned short* __restrict__ AOb) {
  __shared__ unsigned short Pl[8][16*72];   // per-wave P tile, stride 72 (144B, 16B-aligned)
  __shared__ float Om[4][16][64];           // kvh=1 partial O
  __shared__ float Ml[4][2][16];            // kvh=1 (m, l)
  const int bid = blockIdx.x;
  const int qt = bid & 15;     // q-tile (64 rows)
  const int bh = bid >> 4;     // 0..31  (b*H + h)
  const int tid = threadIdx.x, wid = tid >> 6, lane = tid & 63;
  const int qw = wid & 3, kvh = wid >> 2;
  const int lg = lane >> 4, lr = lane & 15;
  const unsigned short* Q  = Qb  + (size_t)bh*S_*DH_;
  const unsigned short* Kp = Kb  + (size_t)bh*S_*DH_;
  const unsigned short* Vt = Vtb + (size_t)bh*DH_*S_;
  const int q0 = qt*64 + qw*16;

  // Hoisted Q A-fragments (A: row=lr, k=lg*8+t), DH=64 -> 2 k-steps
  bf16x8 qf0 = *(const bf16x8*)&Q[(q0 + lr)*DH_ + lg*8];
  bf16x8 qf1 = *(const bf16x8*)&Q[(q0 + lr)*DH_ + 32 + lg*8];

  float mrun[4], lrun[4], corr[4];
  f32x4 o[4] = {};
  #pragma unroll
  for (int i = 0; i < 4; ++i) { mrun[i] = -1e30f; lrun[i] = 0.f; }

  const int jbase = kvh * 512;
  for (int jj = 0; jj < 512; jj += 64) {
    const int j = jbase + jj;
    // QK^T: 4 key-frags x 2 dh-chunks. Score C-layout: row=q=lg*4+i, col=key=lr.
    f32x4 sv[4];
    #pragma unroll
    for (int f = 0; f < 4; ++f) {
      bf16x8 kfa = *(const bf16x8*)&Kp[(size_t)(j + f*16 + lr)*DH_ + lg*8];
      bf16x8 kfb = *(const bf16x8*)&Kp[(size_t)(j + f*16 + lr)*DH_ + 32 + lg*8];
      f32x4 z = {};
      z = __builtin_amdgcn_mfma_f32_16x16x32_bf16(qf0, kfa, z, 0, 0, 0);
      sv[f] = __builtin_amdgcn_mfma_f32_16x16x32_bf16(qf1, kfb, z, 0, 0, 0);
    }
    // V preload — independent of softmax, hides L2 latency under the shfl chain
    bf16x8 vf[2][4];
    #pragma unroll
    for (int c = 0; c < 2; ++c)
      #pragma unroll
      for (int d = 0; d < 4; ++d)
        vf[c][d] = *(const bf16x8*)&Vt[(size_t)(d*16 + lr)*S_ + j + c*32 + lg*8];
    // Online softmax over 64 keys: 4 in-lane frags + 4-level shfl across lr
    #pragma unroll
    for (int i = 0; i < 4; ++i) {
      float a0 = sv[0][i]*0.125f, a1 = sv[1][i]*0.125f;
      float a2 = sv[2][i]*0.125f, a3 = sv[3][i]*0.125f;
      float mx = fmaxf(fmaxf(a0, a1), fmaxf(a2, a3));
      mx = fmaxf(mx, __shfl_xor(mx, 1));
      mx = fmaxf(mx, __shfl_xor(mx, 2));
      mx = fmaxf(mx, __shfl_xor(mx, 4));
      mx = fmaxf(mx, __shfl_xor(mx, 8));
      float mnew = fmaxf(mrun[i], mx);
      float cr = __expf(mrun[i] - mnew);
      float p0 = __expf(a0 - mnew), p1 = __expf(a1 - mnew);
      float p2 = __expf(a2 - mnew), p3 = __expf(a3 - mnew);
      float rs = (p0 + p1) + (p2 + p3);
      rs += __shfl_xor(rs, 1);
      rs += __shfl_xor(rs, 2);
      rs += __shfl_xor(rs, 4);
      rs += __shfl_xor(rs, 8);
      lrun[i] = lrun[i]*cr + rs;
      mrun[i] = mnew;
      corr[i] = cr;
      const int prow = (lg*4 + i)*72;
      Pl[wid][prow +      lr] = f2bf(p0);
      Pl[wid][prow + 16 + lr] = f2bf(p1);
      Pl[wid][prow + 32 + lr] = f2bf(p2);
      Pl[wid][prow + 48 + lr] = f2bf(p3);
    }
    #pragma unroll
    for (int d = 0; d < 4; ++d) {
      o[d][0] *= corr[0]; o[d][1] *= corr[1];
      o[d][2] *= corr[2]; o[d][3] *= corr[3];
    }
    asm volatile("s_waitcnt lgkmcnt(0)" ::: "memory");
    // P A-frag: row=q=lr, k(chunk c) = c*32 + lg*8 + t (wave-private LDS)
    #pragma unroll
    for (int c = 0; c < 2; ++c) {
      bf16x8 pa = *(const bf16x8*)&Pl[wid][lr*72 + c*32 + lg*8];
      #pragma unroll
      for (int d = 0; d < 4; ++d)
        o[d] = __builtin_amdgcn_mfma_f32_16x16x32_bf16(pa, vf[c][d], o[d], 0, 0, 0);
    }
  }

  // --- merge the two KV halves ---
  if (kvh == 1) {
    #pragma unroll
    for (int d = 0; d < 4; ++d)
      #pragma unroll
      for (int i = 0; i < 4; ++i)
        Om[qw][lg*4 + i][d*16 + lr] = o[d][i];
    if (lr == 0) {
      #pragma unroll
      for (int i = 0; i < 4; ++i) {
        Ml[qw][0][lg*4 + i] = mrun[i];
        Ml[qw][1][lg*4 + i] = lrun[i];
      }
    }
  }
  __syncthreads();
  if (kvh == 0) {
    const int b = bh >> 4, hh = bh & 15;
    float c1[4], c2[4], inv[4];
    #pragma unroll
    for (int i = 0; i < 4; ++i) {
      float m2 = Ml[qw][0][lg*4 + i];
      float l2 = Ml[qw][1][lg*4 + i];
      float m  = fmaxf(mrun[i], m2);
      c1[i] = __expf(mrun[i] - m);
      c2[i] = __expf(m2 - m);
      inv[i] = 1.0f / (lrun[i]*c1[i] + l2*c2[i]);
    }
    #pragma unroll
    for (int d = 0; d < 4; ++d)
      #pragma unroll
      for (int i = 0; i < 4; ++i) {
        const int q = q0 + lg*4 + i;
        float ov = o[d][i]*c1[i] + Om[qw][lg*4 + i][d*16 + lr]*c2[i];
        AOb[(size_t)(b*S_ + q)*D_ + hh*DH_ + d*16 + lr] = f2bf(ov * inv[i]);
      }
  }
}

// ---------------------------------------------------------------------------
extern "C" void kernel_launch(void* const* d_in, const int* in_sizes, int n_in,
                              void* d_out, int out_size, void* d_ws, size_t ws_size,
                              hipStream_t stream) {
  const float* x  = (const float*)d_in[0];   // [B,S,D]
  const float* wq = (const float*)d_in[1];   // [3D,D]
  const float* wo = (const float*)d_in[2];   // [D,D]
  float* out = (float*)d_out;                // [B,S,D] fp32

  unsigned short* w = (unsigned short*)d_ws;
  unsigned short* xb  = w;                   // 2097152 bf16
  unsigned short* wqb = xb  + 2097152;       // 3145728
  unsigned short* wob = wqb + 3145728;       // 1048576
  unsigned short* qb  = wob + 1048576;       // 2097152  Q [B,H,S,DH]
  unsigned short* kb  = qb  + 2097152;       // 2097152  K [B,H,S,DH]
  unsigned short* vtb = kb  + 2097152;       // 2097152  V^T [B,H,DH,S]
  unsigned short* aob = vtb + 2097152;       // 2097152  attn out [B,S,D]
  // total ws use: ~25.2 MB

  cvt_kernel<<<dim3(1024), dim3(256), 0, stream>>>(
      (const float4*)x, (const float4*)wq, (const float4*)wo, xb, wqb, wob);

  // QKV projection: M=2048 (B*S), N=3072 (3D), K=1024
  gemm_bt<2048, 3072, 1024, 1><<<dim3(16*24), dim3(256), 0, stream>>>(
      xb, wqb, nullptr, qb, kb, vtb);

  attn_kernel<<<dim3(512), dim3(512), 0, stream>>>(qb, kb, vtb, aob);

  // Output projection: M=2048, N=1024, K=1024
  gemm_bt<2048, 1024, 1024, 0><<<dim3(16*8), dim3(256), 0, stream>>>(
      aob, wob, out, nullptr, nullptr, nullptr);
}

// Round 4
// 182.135 us; speedup vs baseline: 1.0003x; 1.0003x over previous
//
#include <hip/hip_runtime.h>

// Problem dims (fixed)
#define B_  2
#define S_  1024
#define D_  1024
#define H_  16
#define DH_ 64

typedef __attribute__((ext_vector_type(8))) short bf16x8;
typedef __attribute__((ext_vector_type(4))) float f32x4;

__device__ __forceinline__ unsigned short f2bf(float f) {
  unsigned int u = __float_as_uint(f);
  u += 0x7fff + ((u >> 16) & 1);   // round-to-nearest-even
  return (unsigned short)(u >> 16);
}

__device__ __forceinline__ void gload_lds16(const void* g, void* l) {
  __builtin_amdgcn_global_load_lds(
      (const __attribute__((address_space(1))) unsigned int*)g,
      (__attribute__((address_space(3))) unsigned int*)l, 16, 0, 0);
}

// ---------------------------------------------------------------------------
// Kernel 1: fp32 -> bf16 convert for x, W_qkv, W_out
// ---------------------------------------------------------------------------
__global__ __launch_bounds__(256)
void cvt_kernel(const float4* __restrict__ x, const float4* __restrict__ wq,
                const float4* __restrict__ wo, unsigned short* __restrict__ xb,
                unsigned short* __restrict__ wqb, unsigned short* __restrict__ wob) {
  constexpr int n1 = (B_*S_*D_) / 4;       // 524288
  constexpr int n2 = (3*D_*D_) / 4;        // 786432
  constexpr int n3 = (D_*D_) / 4;          // 262144
  for (int i = blockIdx.x*blockDim.x + threadIdx.x; i < n1+n2+n3;
       i += gridDim.x*blockDim.x) {
    const float4* src; unsigned short* dst; int off;
    if (i < n1)          { src = x;  dst = xb;  off = i; }
    else if (i < n1+n2)  { src = wq; dst = wqb; off = i - n1; }
    else                 { src = wo; dst = wob; off = i - n1 - n2; }
    float4 v = src[off];
    ushort4 r;
    r.x = f2bf(v.x); r.y = f2bf(v.y); r.z = f2bf(v.z); r.w = f2bf(v.w);
    *(ushort4*)&dst[off*4] = r;
  }
}

// ---------------------------------------------------------------------------
// GEMM C = A @ Bw^T, A:[M,K] bf16 row-major, Bw:[N,K] bf16 row-major.
// 2-phase double-buffered: STAGE(t+1) issued BEFORE compute(t); one barrier
// per K-step (its implicit vmcnt(0)/lgkmcnt(0) drain provides both the
// next-buffer-ready and current-buffer-consumed guarantees).
// BM x 128 tile, BK=32, 4 waves (2x2), wave tile (BM/2) x 64.
// EPI=0: store fp32 C.  EPI=1: scatter Q/K [B,H,S,DH] and Vt [B,H,DH,S] bf16.
// ---------------------------------------------------------------------------
template<int BM, int M, int N, int K, int EPI>
__global__ __launch_bounds__(256)
void gemm_bt(const unsigned short* __restrict__ A, const unsigned short* __restrict__ Bw,
             float* __restrict__ C, unsigned short* __restrict__ Qb,
             unsigned short* __restrict__ Kb, unsigned short* __restrict__ Vtb) {
  constexpr int NBN = N / 128;
  constexpr int MT  = BM / 32;     // M-frags per wave
  constexpr int AH  = BM / 64;     // A-stage gloads per thread
  constexpr int NSTEP = K / 32;
  __shared__ unsigned short As[2][BM*32];
  __shared__ unsigned short Bs[2][128*32];
  const int tid = threadIdx.x;
  const int bid = blockIdx.x;
  const int mb = bid / NBN, nb = bid % NBN;
  const int wid = tid >> 6, lane = tid & 63;
  const int wr = wid >> 1, wc = wid & 1;
  const int lg = lane >> 4, lr = lane & 15;
  const int mrow = mb*BM, nrow = nb*128;
  const int srow = tid >> 2;       // 0..63
  const int scol = (tid & 3) * 8;  // 0,8,16,24

  f32x4 acc[MT][4] = {};

  auto STAGE = [&](int k0, int buf) {
    #pragma unroll
    for (int h = 0; h < AH; ++h)
      gload_lds16(A  + (size_t)(mrow + h*64 + srow)*K + k0 + scol, &As[buf][(h*256 + tid)*8]);
    #pragma unroll
    for (int h = 0; h < 2; ++h)
      gload_lds16(Bw + (size_t)(nrow + h*64 + srow)*K + k0 + scol, &Bs[buf][(h*256 + tid)*8]);
  };

  STAGE(0, 0);
  __syncthreads();                  // vmcnt(0) drain + barrier
  int buf = 0;
  for (int t = 0; t < NSTEP; ++t) {
    if (t + 1 < NSTEP) STAGE((t+1)*32, buf ^ 1);   // prefetch overlaps compute
    bf16x8 af[MT], bfr[4];
    #pragma unroll
    for (int m = 0; m < MT; ++m)
      af[m] = *(const bf16x8*)&As[buf][(wr*(BM/2) + m*16 + lr)*32 + lg*8];
    #pragma unroll
    for (int n = 0; n < 4; ++n)
      bfr[n] = *(const bf16x8*)&Bs[buf][(wc*64 + n*16 + lr)*32 + lg*8];
    #pragma unroll
    for (int m = 0; m < MT; ++m)
      #pragma unroll
      for (int n = 0; n < 4; ++n)
        acc[m][n] = __builtin_amdgcn_mfma_f32_16x16x32_bf16(af[m], bfr[n], acc[m][n], 0, 0, 0);
    __syncthreads();                // drains prefetch + protects buffer swap
    buf ^= 1;
  }

  // Epilogue. C/D layout: row = lg*4 + i, col = lr  (verified m89/m91).
  #pragma unroll
  for (int mt = 0; mt < MT; ++mt) {
    const int m0 = mrow + wr*(BM/2) + mt*16 + lg*4;
    #pragma unroll
    for (int nt = 0; nt < 4; ++nt) {
      const int n = nrow + wc*64 + nt*16 + lr;
      f32x4 v = acc[mt][nt];
      if constexpr (EPI == 0) {
        #pragma unroll
        for (int i = 0; i < 4; ++i) C[(size_t)(m0 + i)*N + n] = v[i];
      } else {
        const int t3 = n >> 10, rem = n & 1023;
        const int hh = rem >> 6, dh = rem & 63;
        const int b = m0 >> 10, s0 = m0 & 1023;  // all 4 i share b
        if (t3 == 2) {
          // V transposed: Vt[b,h,dh,s]; 4 consecutive s -> one 8B store
          ushort4 pk;
          pk.x = f2bf(v[0]); pk.y = f2bf(v[1]); pk.z = f2bf(v[2]); pk.w = f2bf(v[3]);
          *(ushort4*)&Vtb[(size_t)((b*H_ + hh)*DH_ + dh)*S_ + s0] = pk;
        } else {
          unsigned short* dst = (t3 == 0) ? Qb : Kb;  // [b,h,s,dh]
          #pragma unroll
          for (int i = 0; i < 4; ++i)
            dst[(size_t)((b*H_ + hh)*S_ + s0 + i)*DH_ + dh] = f2bf(v[i]);
        }
      }
    }
  }
}

// ---------------------------------------------------------------------------
// Flash attention v3. Grid 512 blocks, 512 thr = 8 waves (4 q-subtiles x 2 KV
// halves). XCD-locality swizzle: physical XCD = bid%8 (round-robin dispatch),
// so decode bh from bid%8 -> all 16 q-tiles of a head + 3 sibling heads share
// one XCD L2 (working set 1.5MB << 4MB; was 8MB -> thrash -> HBM-latency
// bound at 65us regardless of occupancy).
// ---------------------------------------------------------------------------
__global__ __launch_bounds__(512, 4)
void attn_kernel(const unsigned short* __restrict__ Qb, const unsigned short* __restrict__ Kb,
                 const unsigned short* __restrict__ Vtb, unsigned short* __restrict__ AOb) {
  __shared__ unsigned short Pl[8][16*72];   // per-wave P tile, stride 72 (144B, 16B-aligned)
  __shared__ float Om[4][16][64];           // kvh=1 partial O
  __shared__ float Ml[4][2][16];            // kvh=1 (m, l)
  const int bid = blockIdx.x;
  const int xcd = bid & 7, rr = bid >> 3;
  const int qt = rr & 15;                   // q-tile (64 rows)
  const int bh = (rr >> 4) * 8 + xcd;       // 0..31  (b*H + h), XCD-local
  const int tid = threadIdx.x, wid = tid >> 6, lane = tid & 63;
  const int qw = wid & 3, kvh = wid >> 2;
  const int lg = lane >> 4, lr = lane & 15;
  const unsigned short* Q  = Qb  + (size_t)bh*S_*DH_;
  const unsigned short* Kp = Kb  + (size_t)bh*S_*DH_;
  const unsigned short* Vt = Vtb + (size_t)bh*DH_*S_;
  const int q0 = qt*64 + qw*16;

  // Hoisted Q A-fragments (A: row=lr, k=lg*8+t), DH=64 -> 2 k-steps
  bf16x8 qf0 = *(const bf16x8*)&Q[(q0 + lr)*DH_ + lg*8];
  bf16x8 qf1 = *(const bf16x8*)&Q[(q0 + lr)*DH_ + 32 + lg*8];

  float mrun[4], lrun[4], corr[4];
  f32x4 o[4] = {};
  #pragma unroll
  for (int i = 0; i < 4; ++i) { mrun[i] = -1e30f; lrun[i] = 0.f; }

  const int jbase = kvh * 512;
  for (int jj = 0; jj < 512; jj += 64) {
    const int j = jbase + jj;
    // QK^T: 4 key-frags x 2 dh-chunks. Score C-layout: row=q=lg*4+i, col=key=lr.
    f32x4 sv[4];
    #pragma unroll
    for (int f = 0; f < 4; ++f) {
      bf16x8 kfa = *(const bf16x8*)&Kp[(size_t)(j + f*16 + lr)*DH_ + lg*8];
      bf16x8 kfb = *(const bf16x8*)&Kp[(size_t)(j + f*16 + lr)*DH_ + 32 + lg*8];
      f32x4 z = {};
      z = __builtin_amdgcn_mfma_f32_16x16x32_bf16(qf0, kfa, z, 0, 0, 0);
      sv[f] = __builtin_amdgcn_mfma_f32_16x16x32_bf16(qf1, kfb, z, 0, 0, 0);
    }
    // V preload — independent of softmax, hides load latency under shfl chain
    bf16x8 vf[2][4];
    #pragma unroll
    for (int c = 0; c < 2; ++c)
      #pragma unroll
      for (int d = 0; d < 4; ++d)
        vf[c][d] = *(const bf16x8*)&Vt[(size_t)(d*16 + lr)*S_ + j + c*32 + lg*8];
    // Online softmax over 64 keys: 4 in-lane frags + 4-level shfl across lr
    #pragma unroll
    for (int i = 0; i < 4; ++i) {
      float a0 = sv[0][i]*0.125f, a1 = sv[1][i]*0.125f;
      float a2 = sv[2][i]*0.125f, a3 = sv[3][i]*0.125f;
      float mx = fmaxf(fmaxf(a0, a1), fmaxf(a2, a3));
      mx = fmaxf(mx, __shfl_xor(mx, 1));
      mx = fmaxf(mx, __shfl_xor(mx, 2));
      mx = fmaxf(mx, __shfl_xor(mx, 4));
      mx = fmaxf(mx, __shfl_xor(mx, 8));
      float mnew = fmaxf(mrun[i], mx);
      float cr = __expf(mrun[i] - mnew);
      float p0 = __expf(a0 - mnew), p1 = __expf(a1 - mnew);
      float p2 = __expf(a2 - mnew), p3 = __expf(a3 - mnew);
      float rs = (p0 + p1) + (p2 + p3);
      rs += __shfl_xor(rs, 1);
      rs += __shfl_xor(rs, 2);
      rs += __shfl_xor(rs, 4);
      rs += __shfl_xor(rs, 8);
      lrun[i] = lrun[i]*cr + rs;
      mrun[i] = mnew;
      corr[i] = cr;
      const int prow = (lg*4 + i)*72;
      Pl[wid][prow +      lr] = f2bf(p0);
      Pl[wid][prow + 16 + lr] = f2bf(p1);
      Pl[wid][prow + 32 + lr] = f2bf(p2);
      Pl[wid][prow + 48 + lr] = f2bf(p3);
    }
    #pragma unroll
    for (int d = 0; d < 4; ++d) {
      o[d][0] *= corr[0]; o[d][1] *= corr[1];
      o[d][2] *= corr[2]; o[d][3] *= corr[3];
    }
    asm volatile("s_waitcnt lgkmcnt(0)" ::: "memory");
    // P A-frag: row=q=lr, k(chunk c) = c*32 + lg*8 + t (wave-private LDS)
    #pragma unroll
    for (int c = 0; c < 2; ++c) {
      bf16x8 pa = *(const bf16x8*)&Pl[wid][lr*72 + c*32 + lg*8];
      #pragma unroll
      for (int d = 0; d < 4; ++d)
        o[d] = __builtin_amdgcn_mfma_f32_16x16x32_bf16(pa, vf[c][d], o[d], 0, 0, 0);
    }
  }

  // --- merge the two KV halves ---
  if (kvh == 1) {
    #pragma unroll
    for (int d = 0; d < 4; ++d)
      #pragma unroll
      for (int i = 0; i < 4; ++i)
        Om[qw][lg*4 + i][d*16 + lr] = o[d][i];
    if (lr == 0) {
      #pragma unroll
      for (int i = 0; i < 4; ++i) {
        Ml[qw][0][lg*4 + i] = mrun[i];
        Ml[qw][1][lg*4 + i] = lrun[i];
      }
    }
  }
  __syncthreads();
  if (kvh == 0) {
    const int b = bh >> 4, hh = bh & 15;
    float c1[4], c2[4], inv[4];
    #pragma unroll
    for (int i = 0; i < 4; ++i) {
      float m2 = Ml[qw][0][lg*4 + i];
      float l2 = Ml[qw][1][lg*4 + i];
      float m  = fmaxf(mrun[i], m2);
      c1[i] = __expf(mrun[i] - m);
      c2[i] = __expf(m2 - m);
      inv[i] = 1.0f / (lrun[i]*c1[i] + l2*c2[i]);
    }
    #pragma unroll
    for (int d = 0; d < 4; ++d)
      #pragma unroll
      for (int i = 0; i < 4; ++i) {
        const int q = q0 + lg*4 + i;
        float ov = o[d][i]*c1[i] + Om[qw][lg*4 + i][d*16 + lr]*c2[i];
        AOb[(size_t)(b*S_ + q)*D_ + hh*DH_ + d*16 + lr] = f2bf(ov * inv[i]);
      }
  }
}

// ---------------------------------------------------------------------------
extern "C" void kernel_launch(void* const* d_in, const int* in_sizes, int n_in,
                              void* d_out, int out_size, void* d_ws, size_t ws_size,
                              hipStream_t stream) {
  const float* x  = (const float*)d_in[0];   // [B,S,D]
  const float* wq = (const float*)d_in[1];   // [3D,D]
  const float* wo = (const float*)d_in[2];   // [D,D]
  float* out = (float*)d_out;                // [B,S,D] fp32

  unsigned short* w = (unsigned short*)d_ws;
  unsigned short* xb  = w;                   // 2097152 bf16
  unsigned short* wqb = xb  + 2097152;       // 3145728
  unsigned short* wob = wqb + 3145728;       // 1048576
  unsigned short* qb  = wob + 1048576;       // 2097152  Q [B,H,S,DH]
  unsigned short* kb  = qb  + 2097152;       // 2097152  K [B,H,S,DH]
  unsigned short* vtb = kb  + 2097152;       // 2097152  V^T [B,H,DH,S]
  unsigned short* aob = vtb + 2097152;       // 2097152  attn out [B,S,D]
  // total ws use: ~25.2 MB

  cvt_kernel<<<dim3(1024), dim3(256), 0, stream>>>(
      (const float4*)x, (const float4*)wq, (const float4*)wo, xb, wqb, wob);

  // QKV projection: M=2048 (B*S), N=3072 (3D), K=1024
  gemm_bt<128, 2048, 3072, 1024, 1><<<dim3(16*24), dim3(256), 0, stream>>>(
      xb, wqb, nullptr, qb, kb, vtb);

  attn_kernel<<<dim3(512), dim3(512), 0, stream>>>(qb, kb, vtb, aob);

  // Output projection: M=2048, N=1024, K=1024 — BM=64 -> 256 blocks (1/CU)
  gemm_bt<64, 2048, 1024, 1024, 0><<<dim3(32*8), dim3(256), 0, stream>>>(
      aob, wob, out, nullptr, nullptr, nullptr);
}

// Round 5
// 146.462 us; speedup vs baseline: 1.2439x; 1.2436x over previous
//
#include <hip/hip_runtime.h>

// Problem dims (fixed)
#define B_  2
#define S_  1024
#define D_  1024
#define H_  16
#define DH_ 64

typedef __attribute__((ext_vector_type(8))) short bf16x8;
typedef __attribute__((ext_vector_type(4))) float f32x4;

__device__ __forceinline__ unsigned short f2bf(float f) {
  unsigned int u = __float_as_uint(f);
  u += 0x7fff + ((u >> 16) & 1);   // round-to-nearest-even
  return (unsigned short)(u >> 16);
}

__device__ __forceinline__ unsigned int pack2bf(float a, float b) {
  return (unsigned int)f2bf(a) | ((unsigned int)f2bf(b) << 16);
}

__device__ __forceinline__ void gload_lds16(const void* g, void* l) {
  __builtin_amdgcn_global_load_lds(
      (const __attribute__((address_space(1))) unsigned int*)g,
      (__attribute__((address_space(3))) unsigned int*)l, 16, 0, 0);
}

// ---------------------------------------------------------------------------
// Kernel 1: fp32 -> bf16 convert for x, W_qkv, W_out
// ---------------------------------------------------------------------------
__global__ __launch_bounds__(256)
void cvt_kernel(const float4* __restrict__ x, const float4* __restrict__ wq,
                const float4* __restrict__ wo, unsigned short* __restrict__ xb,
                unsigned short* __restrict__ wqb, unsigned short* __restrict__ wob) {
  constexpr int n1 = (B_*S_*D_) / 4;       // 524288
  constexpr int n2 = (3*D_*D_) / 4;        // 786432
  constexpr int n3 = (D_*D_) / 4;          // 262144
  for (int i = blockIdx.x*blockDim.x + threadIdx.x; i < n1+n2+n3;
       i += gridDim.x*blockDim.x) {
    const float4* src; unsigned short* dst; int off;
    if (i < n1)          { src = x;  dst = xb;  off = i; }
    else if (i < n1+n2)  { src = wq; dst = wqb; off = i - n1; }
    else                 { src = wo; dst = wob; off = i - n1 - n2; }
    float4 v = src[off];
    ushort4 r;
    r.x = f2bf(v.x); r.y = f2bf(v.y); r.z = f2bf(v.z); r.w = f2bf(v.w);
    *(ushort4*)&dst[off*4] = r;
  }
}

// ---------------------------------------------------------------------------
// GEMM C = A @ Bw^T  (R2-verified single-buffer m97 structure, reverted)
// 128x128 tile, BK=32, global_load_lds(16B), 4 waves (2x2), 4x4 frags.
// EPI=0: store fp32 C.  EPI=1: scatter Q/K [B,H,S,DH] and Vt [B,H,DH,S] bf16.
// ---------------------------------------------------------------------------
template<int M, int N, int K, int EPI>
__global__ __launch_bounds__(256)
void gemm_bt(const unsigned short* __restrict__ A, const unsigned short* __restrict__ Bw,
             float* __restrict__ C, unsigned short* __restrict__ Qb,
             unsigned short* __restrict__ Kb, unsigned short* __restrict__ Vtb) {
  constexpr int NBN = N / 128;
  __shared__ unsigned short As[128*32];
  __shared__ unsigned short Bs[128*32];
  const int tid = threadIdx.x;
  const int bid = blockIdx.x;
  const int mb = bid / NBN, nb = bid % NBN;
  const int wid = tid >> 6, lane = tid & 63;
  const int wr = wid >> 1, wc = wid & 1;
  const int lg = lane >> 4, lr = lane & 15;

  f32x4 acc[4][4] = {};

  const int mrow = mb*128, nrow = nb*128;
  const int srow = tid >> 2;       // 0..63
  const int scol = (tid & 3) * 8;  // 0,8,16,24

  for (int k0 = 0; k0 < K; k0 += 32) {
    #pragma unroll
    for (int h = 0; h < 2; ++h) {
      gload_lds16(A  + (size_t)(mrow + h*64 + srow)*K + k0 + scol, &As[(h*256 + tid)*8]);
      gload_lds16(Bw + (size_t)(nrow + h*64 + srow)*K + k0 + scol, &Bs[(h*256 + tid)*8]);
    }
    __syncthreads();
    bf16x8 af[4], bfr[4];
    #pragma unroll
    for (int t = 0; t < 4; ++t) {
      af[t]  = *(const bf16x8*)&As[(wr*64 + t*16 + lr)*32 + lg*8];
      bfr[t] = *(const bf16x8*)&Bs[(wc*64 + t*16 + lr)*32 + lg*8];
    }
    #pragma unroll
    for (int mt = 0; mt < 4; ++mt)
      #pragma unroll
      for (int nt = 0; nt < 4; ++nt)
        acc[mt][nt] = __builtin_amdgcn_mfma_f32_16x16x32_bf16(af[mt], bfr[nt], acc[mt][nt], 0, 0, 0);
    __syncthreads();
  }

  // Epilogue. C/D layout: row = lg*4 + i, col = lr  (verified m89/m91).
  #pragma unroll
  for (int mt = 0; mt < 4; ++mt) {
    const int m0 = mrow + wr*64 + mt*16 + lg*4;
    #pragma unroll
    for (int nt = 0; nt < 4; ++nt) {
      const int n = nrow + wc*64 + nt*16 + lr;
      f32x4 v = acc[mt][nt];
      if constexpr (EPI == 0) {
        #pragma unroll
        for (int i = 0; i < 4; ++i) C[(size_t)(m0 + i)*N + n] = v[i];
      } else {
        const int t3 = n >> 10, rem = n & 1023;
        const int hh = rem >> 6, dh = rem & 63;
        const int b = m0 >> 10, s0 = m0 & 1023;
        if (t3 == 2) {
          ushort4 pk;
          pk.x = f2bf(v[0]); pk.y = f2bf(v[1]); pk.z = f2bf(v[2]); pk.w = f2bf(v[3]);
          *(ushort4*)&Vtb[(size_t)((b*H_ + hh)*DH_ + dh)*S_ + s0] = pk;
        } else {
          unsigned short* dst = (t3 == 0) ? Qb : Kb;
          #pragma unroll
          for (int i = 0; i < 4; ++i)
            dst[(size_t)((b*H_ + hh)*S_ + s0 + i)*DH_ + dh] = f2bf(v[i]);
        }
      }
    }
  }
}

// ---------------------------------------------------------------------------
// Flash attention v4.
// Grid: B*H*(S/128) = 256 blocks (1/CU), 512 thr = 8 waves, wave owns 16 q.
// K/V staged ONCE per block into double-buffered LDS tiles (64 keys):
//   Ks[buf][key][dh]  8KB,  Vs[buf][d][key] 8KB  — via global_load_lds with
//   pre-swizzled SOURCE chunks (cl = cw ^ (row&7)) + swizzled reads (T2/#21)
//   -> conflict-free ds_read_b128, and per-block L2 traffic 1MB -> 256KB
//   (R1/R2/R4 all pinned at 65.4us by redundant per-wave K/V streams through
//   the L1-miss path; fetch/occupancy changes didn't move it).
// Swapped QK^T: sv = mfma(K,Q) -> lane holds S^T[key=16f+lg*4+i][q=lr]:
//   softmax = in-lane tree over 16 + 2 shfl levels (xor16/32); m,l scalar.
// PV swapped: o[dt] = mfma(Vs-frag, P-frag) accumulates O^T[d][q=lr];
//   P via per-wave padded LDS tile (stride 72 shorts = 9x16B).
// XCD swizzle: bh = (rr>>3)*8 + bid%8 -> 4 heads/XCD (~1MB KV, L2-resident).
// ---------------------------------------------------------------------------
__global__ __launch_bounds__(512, 2)
void attn_kernel(const unsigned short* __restrict__ Qb, const unsigned short* __restrict__ Kb,
                 const unsigned short* __restrict__ Vtb, unsigned short* __restrict__ AOb) {
  __shared__ unsigned short Ks[2][64*64];
  __shared__ unsigned short Vs[2][64*64];
  __shared__ unsigned short Pl[8][16*72];
  const int bid = blockIdx.x;
  const int xcd = bid & 7, rr = bid >> 3;
  const int qt = rr & 7;                    // q-tile of 128 rows
  const int bh = (rr >> 3) * 8 + xcd;       // 0..31, XCD-local heads
  const int tid = threadIdx.x, wid = tid >> 6, lane = tid & 63;
  const int lg = lane >> 4, lr = lane & 15;
  const unsigned short* Q  = Qb  + (size_t)bh*S_*DH_;
  const unsigned short* Kp = Kb  + (size_t)bh*S_*DH_;
  const unsigned short* Vt = Vtb + (size_t)bh*DH_*S_;
  const int q0 = qt*128 + wid*16;

  // Q B-fragments (col=q=lr, k=lg*8+t), dh chunks 0 / 32
  bf16x8 qf0 = *(const bf16x8*)&Q[(size_t)(q0 + lr)*DH_ + lg*8];
  bf16x8 qf1 = *(const bf16x8*)&Q[(size_t)(q0 + lr)*DH_ + 32 + lg*8];

  // staging: 512 thr cover 64 rows x 8 chunks of 16B; source chunk swizzled
  const int sr = tid >> 3;          // row 0..63
  const int gc = (tid & 7) ^ (sr & 7);   // global chunk for this lds slot

  float mrun = -1e30f, lrun = 0.f;
  f32x4 o[4] = {};
  const int rsw = lr & 7;           // read-side swizzle key

  // prologue stage tile 0
  gload_lds16(Kp + (size_t)sr*DH_ + gc*8,  &Ks[0][tid*8]);
  gload_lds16(Vt + (size_t)sr*S_  + gc*8,  &Vs[0][tid*8]);
  __syncthreads();

  int buf = 0;
  for (int t = 0; t < 16; ++t) {
    const int jn = (t + 1) * 64;
    if (t < 15) {
      gload_lds16(Kp + (size_t)(jn + sr)*DH_ + gc*8, &Ks[buf^1][tid*8]);
      gload_lds16(Vt + (size_t)sr*S_ + jn + gc*8,    &Vs[buf^1][tid*8]);
    }
    // QK^T swapped: sv[f] = S^T rows 16f+lg*4+i, col q=lr
    f32x4 sv[4];
    #pragma unroll
    for (int f = 0; f < 4; ++f) {
      bf16x8 ka = *(const bf16x8*)&Ks[buf][(16*f + lr)*64 + ((lg     ^ rsw)*8)];
      bf16x8 kb = *(const bf16x8*)&Ks[buf][(16*f + lr)*64 + (((lg+4) ^ rsw)*8)];
      f32x4 z = {};
      z     = __builtin_amdgcn_mfma_f32_16x16x32_bf16(ka, qf0, z, 0, 0, 0);
      sv[f] = __builtin_amdgcn_mfma_f32_16x16x32_bf16(kb, qf1, z, 0, 0, 0);
    }
    // in-lane softmax for q=lr over this lane's 16 keys
    float s[16];
    #pragma unroll
    for (int f = 0; f < 4; ++f)
      #pragma unroll
      for (int i = 0; i < 4; ++i) s[4*f + i] = sv[f][i] * 0.125f;
    float t8[8];
    #pragma unroll
    for (int k = 0; k < 8; ++k) t8[k] = fmaxf(s[k], s[k+8]);
    float t4a = fmaxf(t8[0], t8[4]), t4b = fmaxf(t8[1], t8[5]);
    float t4c = fmaxf(t8[2], t8[6]), t4d = fmaxf(t8[3], t8[7]);
    float pmax = fmaxf(fmaxf(t4a, t4b), fmaxf(t4c, t4d));
    pmax = fmaxf(pmax, __shfl_xor(pmax, 16));
    pmax = fmaxf(pmax, __shfl_xor(pmax, 32));
    float mnew = fmaxf(mrun, pmax);
    float cr = __expf(mrun - mnew);
    float p[16];
    #pragma unroll
    for (int k = 0; k < 16; ++k) p[k] = __expf(s[k] - mnew);
    float u8[8];
    #pragma unroll
    for (int k = 0; k < 8; ++k) u8[k] = p[k] + p[k+8];
    float u4a = u8[0]+u8[4], u4b = u8[1]+u8[5], u4c = u8[2]+u8[6], u4d = u8[3]+u8[7];
    float rs = (u4a + u4b) + (u4c + u4d);
    rs += __shfl_xor(rs, 16);
    rs += __shfl_xor(rs, 32);
    lrun = lrun*cr + rs;
    mrun = mnew;
    // P^T pack -> Pl[q=lr][key], 4x ds_write_b64 (keys 16f+lg*4 .. +3)
    #pragma unroll
    for (int f = 0; f < 4; ++f) {
      uint2 w;
      w.x = pack2bf(p[4*f],   p[4*f+1]);
      w.y = pack2bf(p[4*f+2], p[4*f+3]);
      *(uint2*)&Pl[wid][lr*72 + f*16 + lg*4] = w;
    }
    // rescale O^T by per-lane scalar
    #pragma unroll
    for (int dt = 0; dt < 4; ++dt) {
      o[dt][0] *= cr; o[dt][1] *= cr; o[dt][2] *= cr; o[dt][3] *= cr;
    }
    asm volatile("s_waitcnt lgkmcnt(0)" ::: "memory");
    // PV swapped: o[dt] += Vs[d][k] * P^T[k][q]
    #pragma unroll
    for (int c = 0; c < 2; ++c) {
      bf16x8 pf = *(const bf16x8*)&Pl[wid][lr*72 + c*32 + lg*8];
      #pragma unroll
      for (int dt = 0; dt < 4; ++dt) {
        bf16x8 vfr = *(const bf16x8*)&Vs[buf][(dt*16 + lr)*64 + (((c*4 + lg) ^ rsw)*8)];
        o[dt] = __builtin_amdgcn_mfma_f32_16x16x32_bf16(vfr, pf, o[dt], 0, 0, 0);
      }
    }
    __syncthreads();   // prefetch landed (vmcnt0) + buf consumed by all waves
    buf ^= 1;
  }

  // epilogue: lane holds O^T[d = dt*16+lg*4+i][q = q0+lr]
  const float inv = 1.0f / lrun;
  const int b = bh >> 4, hh = bh & 15;
  #pragma unroll
  for (int dt = 0; dt < 4; ++dt) {
    ushort4 pk;
    pk.x = f2bf(o[dt][0]*inv); pk.y = f2bf(o[dt][1]*inv);
    pk.z = f2bf(o[dt][2]*inv); pk.w = f2bf(o[dt][3]*inv);
    *(ushort4*)&AOb[(size_t)(b*S_ + q0 + lr)*D_ + hh*DH_ + dt*16 + lg*4] = pk;
  }
}

// ---------------------------------------------------------------------------
extern "C" void kernel_launch(void* const* d_in, const int* in_sizes, int n_in,
                              void* d_out, int out_size, void* d_ws, size_t ws_size,
                              hipStream_t stream) {
  const float* x  = (const float*)d_in[0];   // [B,S,D]
  const float* wq = (const float*)d_in[1];   // [3D,D]
  const float* wo = (const float*)d_in[2];   // [D,D]
  float* out = (float*)d_out;                // [B,S,D] fp32

  unsigned short* w = (unsigned short*)d_ws;
  unsigned short* xb  = w;                   // 2097152 bf16
  unsigned short* wqb = xb  + 2097152;       // 3145728
  unsigned short* wob = wqb + 3145728;       // 1048576
  unsigned short* qb  = wob + 1048576;       // 2097152  Q [B,H,S,DH]
  unsigned short* kb  = qb  + 2097152;       // 2097152  K [B,H,S,DH]
  unsigned short* vtb = kb  + 2097152;       // 2097152  V^T [B,H,DH,S]
  unsigned short* aob = vtb + 2097152;       // 2097152  attn out [B,S,D]

  cvt_kernel<<<dim3(1024), dim3(256), 0, stream>>>(
      (const float4*)x, (const float4*)wq, (const float4*)wo, xb, wqb, wob);

  // QKV projection: M=2048 (B*S), N=3072 (3D), K=1024
  gemm_bt<2048, 3072, 1024, 1><<<dim3(16*24), dim3(256), 0, stream>>>(
      xb, wqb, nullptr, qb, kb, vtb);

  attn_kernel<<<dim3(256), dim3(512), 0, stream>>>(qb, kb, vtb, aob);

  // Output projection: M=2048, N=1024, K=1024
  gemm_bt<2048, 1024, 1024, 0><<<dim3(16*8), dim3(256), 0, stream>>>(
      aob, wob, out, nullptr, nullptr, nullptr);
}

// Round 6
// 141.603 us; speedup vs baseline: 1.2866x; 1.0343x over previous
//
#include <hip/hip_runtime.h>

// Problem dims (fixed)
#define B_  2
#define S_  1024
#define D_  1024
#define H_  16
#define DH_ 64

typedef __attribute__((ext_vector_type(8))) short bf16x8;
typedef __attribute__((ext_vector_type(4))) float f32x4;

__device__ __forceinline__ unsigned short f2bf(float f) {
  unsigned int u = __float_as_uint(f);
  u += 0x7fff + ((u >> 16) & 1);   // round-to-nearest-even
  return (unsigned short)(u >> 16);
}

__device__ __forceinline__ unsigned int pack2bf(float a, float b) {
  return (unsigned int)f2bf(a) | ((unsigned int)f2bf(b) << 16);
}

__device__ __forceinline__ void gload_lds16(const void* g, void* l) {
  __builtin_amdgcn_global_load_lds(
      (const __attribute__((address_space(1))) unsigned int*)g,
      (__attribute__((address_space(3))) unsigned int*)l, 16, 0, 0);
}

// ---------------------------------------------------------------------------
// Kernel 1: fp32 -> bf16 convert for x, W_qkv, W_out
// ---------------------------------------------------------------------------
__global__ __launch_bounds__(256)
void cvt_kernel(const float4* __restrict__ x, const float4* __restrict__ wq,
                const float4* __restrict__ wo, unsigned short* __restrict__ xb,
                unsigned short* __restrict__ wqb, unsigned short* __restrict__ wob) {
  constexpr int n1 = (B_*S_*D_) / 4;       // 524288
  constexpr int n2 = (3*D_*D_) / 4;        // 786432
  constexpr int n3 = (D_*D_) / 4;          // 262144
  for (int i = blockIdx.x*blockDim.x + threadIdx.x; i < n1+n2+n3;
       i += gridDim.x*blockDim.x) {
    const float4* src; unsigned short* dst; int off;
    if (i < n1)          { src = x;  dst = xb;  off = i; }
    else if (i < n1+n2)  { src = wq; dst = wqb; off = i - n1; }
    else                 { src = wo; dst = wob; off = i - n1 - n2; }
    float4 v = src[off];
    ushort4 r;
    r.x = f2bf(v.x); r.y = f2bf(v.y); r.z = f2bf(v.z); r.w = f2bf(v.w);
    *(ushort4*)&dst[off*4] = r;
  }
}

// ---------------------------------------------------------------------------
// GEMM C = A @ Bw^T  (single-buffer m97 structure; BM templated).
// BM x 128 tile, BK=32, global_load_lds(16B), 4 waves (2x2), wave tile
// (BM/2) x 64 = MT x 4 frags of 16x16x32 MFMA.
// BM=64 -> 2x the blocks: even blocks/CU + co-residency hides barrier drain.
// EPI=0: store fp32 C.  EPI=1: scatter Q/K [B,H,S,DH] and Vt [B,H,DH,S] bf16.
// ---------------------------------------------------------------------------
template<int BM, int M, int N, int K, int EPI>
__global__ __launch_bounds__(256)
void gemm_bt(const unsigned short* __restrict__ A, const unsigned short* __restrict__ Bw,
             float* __restrict__ C, unsigned short* __restrict__ Qb,
             unsigned short* __restrict__ Kb, unsigned short* __restrict__ Vtb) {
  constexpr int NBN = N / 128;
  constexpr int MT  = BM / 32;     // M-frags per wave
  constexpr int AH  = BM / 64;     // A-stage gloads per thread
  __shared__ unsigned short As[BM*32];
  __shared__ unsigned short Bs[128*32];
  const int tid = threadIdx.x;
  const int bid = blockIdx.x;
  const int mb = bid / NBN, nb = bid % NBN;
  const int wid = tid >> 6, lane = tid & 63;
  const int wr = wid >> 1, wc = wid & 1;
  const int lg = lane >> 4, lr = lane & 15;

  f32x4 acc[MT][4] = {};

  const int mrow = mb*BM, nrow = nb*128;
  const int srow = tid >> 2;       // 0..63
  const int scol = (tid & 3) * 8;  // 0,8,16,24

  for (int k0 = 0; k0 < K; k0 += 32) {
    #pragma unroll
    for (int h = 0; h < AH; ++h)
      gload_lds16(A  + (size_t)(mrow + h*64 + srow)*K + k0 + scol, &As[(h*256 + tid)*8]);
    #pragma unroll
    for (int h = 0; h < 2; ++h)
      gload_lds16(Bw + (size_t)(nrow + h*64 + srow)*K + k0 + scol, &Bs[(h*256 + tid)*8]);
    __syncthreads();
    bf16x8 af[MT], bfr[4];
    #pragma unroll
    for (int m = 0; m < MT; ++m)
      af[m]  = *(const bf16x8*)&As[(wr*(BM/2) + m*16 + lr)*32 + lg*8];
    #pragma unroll
    for (int n = 0; n < 4; ++n)
      bfr[n] = *(const bf16x8*)&Bs[(wc*64 + n*16 + lr)*32 + lg*8];
    #pragma unroll
    for (int m = 0; m < MT; ++m)
      #pragma unroll
      for (int n = 0; n < 4; ++n)
        acc[m][n] = __builtin_amdgcn_mfma_f32_16x16x32_bf16(af[m], bfr[n], acc[m][n], 0, 0, 0);
    __syncthreads();
  }

  // Epilogue. C/D layout: row = lg*4 + i, col = lr  (verified m89/m91).
  #pragma unroll
  for (int mt = 0; mt < MT; ++mt) {
    const int m0 = mrow + wr*(BM/2) + mt*16 + lg*4;
    #pragma unroll
    for (int nt = 0; nt < 4; ++nt) {
      const int n = nrow + wc*64 + nt*16 + lr;
      f32x4 v = acc[mt][nt];
      if constexpr (EPI == 0) {
        #pragma unroll
        for (int i = 0; i < 4; ++i) C[(size_t)(m0 + i)*N + n] = v[i];
      } else {
        const int t3 = n >> 10, rem = n & 1023;
        const int hh = rem >> 6, dh = rem & 63;
        const int b = m0 >> 10, s0 = m0 & 1023;
        if (t3 == 2) {
          ushort4 pk;
          pk.x = f2bf(v[0]); pk.y = f2bf(v[1]); pk.z = f2bf(v[2]); pk.w = f2bf(v[3]);
          *(ushort4*)&Vtb[(size_t)((b*H_ + hh)*DH_ + dh)*S_ + s0] = pk;
        } else {
          unsigned short* dst = (t3 == 0) ? Qb : Kb;
          #pragma unroll
          for (int i = 0; i < 4; ++i)
            dst[(size_t)((b*H_ + hh)*S_ + s0 + i)*DH_ + dh] = f2bf(v[i]);
        }
      }
    }
  }
}

// ---------------------------------------------------------------------------
// Flash attention v5.
// Grid: B*H*(S/64) = 512 blocks, 256 thr = 4 waves, wave owns 16 q-rows.
// LDS ~41KB -> 2 blocks/CU co-resident: independent barrier groups overlap
// each other's vmcnt(0) drains (m114 mechanism; v4 at 1 block/CU stalled the
// whole CU every iteration).
// K/V double-buffered LDS tiles (64 keys), staged via global_load_lds with
// pre-swizzled SOURCE chunks + swizzled reads (T2/#21) -> conflict-free.
// Swapped QK^T (mfma(K,Q)) -> in-lane softmax (16 keys/lane + 2 shfl).
// PV swapped accumulates O^T. T5 setprio around both MFMA clusters.
// XCD swizzle: bh = (rr>>4)*8 + bid%8 -> 4 heads/XCD (~1MB KV, L2-resident).
// ---------------------------------------------------------------------------
__global__ __launch_bounds__(256, 2)
void attn_kernel(const unsigned short* __restrict__ Qb, const unsigned short* __restrict__ Kb,
                 const unsigned short* __restrict__ Vtb, unsigned short* __restrict__ AOb) {
  __shared__ unsigned short Ks[2][64*64];
  __shared__ unsigned short Vs[2][64*64];
  __shared__ unsigned short Pl[4][16*72];
  const int bid = blockIdx.x;
  const int xcd = bid & 7, rr = bid >> 3;
  const int qt = rr & 15;                   // q-tile of 64 rows
  const int bh = (rr >> 4) * 8 + xcd;       // 0..31, XCD-local heads
  const int tid = threadIdx.x, wid = tid >> 6, lane = tid & 63;
  const int lg = lane >> 4, lr = lane & 15;
  const unsigned short* Q  = Qb  + (size_t)bh*S_*DH_;
  const unsigned short* Kp = Kb  + (size_t)bh*S_*DH_;
  const unsigned short* Vt = Vtb + (size_t)bh*DH_*S_;
  const int q0 = qt*64 + wid*16;

  // Q B-fragments (col=q=lr, k=lg*8+t), dh chunks 0 / 32
  bf16x8 qf0 = *(const bf16x8*)&Q[(size_t)(q0 + lr)*DH_ + lg*8];
  bf16x8 qf1 = *(const bf16x8*)&Q[(size_t)(q0 + lr)*DH_ + 32 + lg*8];

  // staging: 256 thr x 2 slots cover 64 rows x 8 chunks of 16B
  // slot s covers row (s>>3), lds-chunk (s&7); stored content = global chunk
  // (s&7) ^ (row&7)  [since +32 preserves &7, both slots share g0]
  const int sr = tid >> 3;               // 0..31
  const int g0 = (tid & 7) ^ (sr & 7);

  float mrun = -1e30f, lrun = 0.f;
  f32x4 o[4] = {};
  const int rsw = lr & 7;                // read-side swizzle key

  // prologue stage tile 0
  gload_lds16(Kp + (size_t)sr*DH_        + g0*8, &Ks[0][tid*8]);
  gload_lds16(Kp + (size_t)(sr+32)*DH_   + g0*8, &Ks[0][(256+tid)*8]);
  gload_lds16(Vt + (size_t)sr*S_         + g0*8, &Vs[0][tid*8]);
  gload_lds16(Vt + (size_t)(sr+32)*S_    + g0*8, &Vs[0][(256+tid)*8]);
  __syncthreads();

  int buf = 0;
  for (int t = 0; t < 16; ++t) {
    const int jn = (t + 1) * 64;
    if (t < 15) {
      gload_lds16(Kp + (size_t)(jn + sr)*DH_      + g0*8, &Ks[buf^1][tid*8]);
      gload_lds16(Kp + (size_t)(jn + sr + 32)*DH_ + g0*8, &Ks[buf^1][(256+tid)*8]);
      gload_lds16(Vt + (size_t)sr*S_      + jn + g0*8,    &Vs[buf^1][tid*8]);
      gload_lds16(Vt + (size_t)(sr+32)*S_ + jn + g0*8,    &Vs[buf^1][(256+tid)*8]);
    }
    // QK^T swapped: sv[f] = S^T rows (keys) 16f+lg*4+i, col q=lr
    f32x4 sv[4];
    __builtin_amdgcn_s_setprio(1);
    #pragma unroll
    for (int f = 0; f < 4; ++f) {
      bf16x8 ka = *(const bf16x8*)&Ks[buf][(16*f + lr)*64 + ((lg     ^ rsw)*8)];
      bf16x8 kb = *(const bf16x8*)&Ks[buf][(16*f + lr)*64 + (((lg+4) ^ rsw)*8)];
      f32x4 z = {};
      z     = __builtin_amdgcn_mfma_f32_16x16x32_bf16(ka, qf0, z, 0, 0, 0);
      sv[f] = __builtin_amdgcn_mfma_f32_16x16x32_bf16(kb, qf1, z, 0, 0, 0);
    }
    __builtin_amdgcn_s_setprio(0);
    // in-lane softmax for q=lr over this lane's 16 keys
    float s[16];
    #pragma unroll
    for (int f = 0; f < 4; ++f)
      #pragma unroll
      for (int i = 0; i < 4; ++i) s[4*f + i] = sv[f][i] * 0.125f;
    float t8[8];
    #pragma unroll
    for (int k = 0; k < 8; ++k) t8[k] = fmaxf(s[k], s[k+8]);
    float t4a = fmaxf(t8[0], t8[4]), t4b = fmaxf(t8[1], t8[5]);
    float t4c = fmaxf(t8[2], t8[6]), t4d = fmaxf(t8[3], t8[7]);
    float pmax = fmaxf(fmaxf(t4a, t4b), fmaxf(t4c, t4d));
    pmax = fmaxf(pmax, __shfl_xor(pmax, 16));
    pmax = fmaxf(pmax, __shfl_xor(pmax, 32));
    float mnew = fmaxf(mrun, pmax);
    float cr = __expf(mrun - mnew);
    float p[16];
    #pragma unroll
    for (int k = 0; k < 16; ++k) p[k] = __expf(s[k] - mnew);
    float u8[8];
    #pragma unroll
    for (int k = 0; k < 8; ++k) u8[k] = p[k] + p[k+8];
    float u4a = u8[0]+u8[4], u4b = u8[1]+u8[5], u4c = u8[2]+u8[6], u4d = u8[3]+u8[7];
    float rs = (u4a + u4b) + (u4c + u4d);
    rs += __shfl_xor(rs, 16);
    rs += __shfl_xor(rs, 32);
    lrun = lrun*cr + rs;
    mrun = mnew;
    // P^T pack -> Pl[q=lr][key], 4x ds_write_b64 (keys 16f+lg*4 .. +3)
    #pragma unroll
    for (int f = 0; f < 4; ++f) {
      uint2 w;
      w.x = pack2bf(p[4*f],   p[4*f+1]);
      w.y = pack2bf(p[4*f+2], p[4*f+3]);
      *(uint2*)&Pl[wid][lr*72 + f*16 + lg*4] = w;
    }
    // rescale O^T by per-lane scalar
    #pragma unroll
    for (int dt = 0; dt < 4; ++dt) {
      o[dt][0] *= cr; o[dt][1] *= cr; o[dt][2] *= cr; o[dt][3] *= cr;
    }
    asm volatile("s_waitcnt lgkmcnt(0)" ::: "memory");
    // PV swapped: o[dt] += Vs[d][k] * P^T[k][q]
    __builtin_amdgcn_s_setprio(1);
    #pragma unroll
    for (int c = 0; c < 2; ++c) {
      bf16x8 pf = *(const bf16x8*)&Pl[wid][lr*72 + c*32 + lg*8];
      #pragma unroll
      for (int dt = 0; dt < 4; ++dt) {
        bf16x8 vfr = *(const bf16x8*)&Vs[buf][(dt*16 + lr)*64 + (((c*4 + lg) ^ rsw)*8)];
        o[dt] = __builtin_amdgcn_mfma_f32_16x16x32_bf16(vfr, pf, o[dt], 0, 0, 0);
      }
    }
    __builtin_amdgcn_s_setprio(0);
    __syncthreads();   // prefetch landed (vmcnt0) + buf consumed by all waves
    buf ^= 1;
  }

  // epilogue: lane holds O^T[d = dt*16+lg*4+i][q = q0+lr]
  const float inv = 1.0f / lrun;
  const int b = bh >> 4, hh = bh & 15;
  #pragma unroll
  for (int dt = 0; dt < 4; ++dt) {
    ushort4 pk;
    pk.x = f2bf(o[dt][0]*inv); pk.y = f2bf(o[dt][1]*inv);
    pk.z = f2bf(o[dt][2]*inv); pk.w = f2bf(o[dt][3]*inv);
    *(ushort4*)&AOb[(size_t)(b*S_ + q0 + lr)*D_ + hh*DH_ + dt*16 + lg*4] = pk;
  }
}

// ---------------------------------------------------------------------------
extern "C" void kernel_launch(void* const* d_in, const int* in_sizes, int n_in,
                              void* d_out, int out_size, void* d_ws, size_t ws_size,
                              hipStream_t stream) {
  const float* x  = (const float*)d_in[0];   // [B,S,D]
  const float* wq = (const float*)d_in[1];   // [3D,D]
  const float* wo = (const float*)d_in[2];   // [D,D]
  float* out = (float*)d_out;                // [B,S,D] fp32

  unsigned short* w = (unsigned short*)d_ws;
  unsigned short* xb  = w;                   // 2097152 bf16
  unsigned short* wqb = xb  + 2097152;       // 3145728
  unsigned short* wob = wqb + 3145728;       // 1048576
  unsigned short* qb  = wob + 1048576;       // 2097152  Q [B,H,S,DH]
  unsigned short* kb  = qb  + 2097152;       // 2097152  K [B,H,S,DH]
  unsigned short* vtb = kb  + 2097152;       // 2097152  V^T [B,H,DH,S]
  unsigned short* aob = vtb + 2097152;       // 2097152  attn out [B,S,D]

  cvt_kernel<<<dim3(1024), dim3(256), 0, stream>>>(
      (const float4*)x, (const float4*)wq, (const float4*)wo, xb, wqb, wob);

  // QKV projection: M=2048, N=3072, K=1024 — BM=64 -> 768 blocks = 3/CU even
  gemm_bt<64, 2048, 3072, 1024, 1><<<dim3(32*24), dim3(256), 0, stream>>>(
      xb, wqb, nullptr, qb, kb, vtb);

  attn_kernel<<<dim3(512), dim3(256), 0, stream>>>(qb, kb, vtb, aob);

  // Output projection: M=2048, N=1024, K=1024 — BM=64 -> 256 blocks = 1/CU
  gemm_bt<64, 2048, 1024, 1024, 0><<<dim3(32*8), dim3(256), 0, stream>>>(
      aob, wob, out, nullptr, nullptr, nullptr);
}

// Round 7
// 140.328 us; speedup vs baseline: 1.2983x; 1.0091x over previous
//
#include <hip/hip_runtime.h>

// Problem dims (fixed)
#define B_  2
#define S_  1024
#define D_  1024
#define H_  16
#define DH_ 64

typedef __attribute__((ext_vector_type(8))) short bf16x8;
typedef __attribute__((ext_vector_type(4))) float f32x4;

__device__ __forceinline__ unsigned short f2bf(float f) {
  unsigned int u = __float_as_uint(f);
  u += 0x7fff + ((u >> 16) & 1);   // round-to-nearest-even
  return (unsigned short)(u >> 16);
}

__device__ __forceinline__ unsigned int pack2bf(float a, float b) {
  return (unsigned int)f2bf(a) | ((unsigned int)f2bf(b) << 16);
}

__device__ __forceinline__ void gload_lds16(const void* g, void* l) {
  __builtin_amdgcn_global_load_lds(
      (const __attribute__((address_space(1))) unsigned int*)g,
      (__attribute__((address_space(3))) unsigned int*)l, 16, 0, 0);
}

// ---------------------------------------------------------------------------
// Kernel 1: fp32 -> bf16 convert for x, W_qkv, W_out
// ---------------------------------------------------------------------------
__global__ __launch_bounds__(256)
void cvt_kernel(const float4* __restrict__ x, const float4* __restrict__ wq,
                const float4* __restrict__ wo, unsigned short* __restrict__ xb,
                unsigned short* __restrict__ wqb, unsigned short* __restrict__ wob) {
  constexpr int n1 = (B_*S_*D_) / 4;       // 524288
  constexpr int n2 = (3*D_*D_) / 4;        // 786432
  constexpr int n3 = (D_*D_) / 4;          // 262144
  for (int i = blockIdx.x*blockDim.x + threadIdx.x; i < n1+n2+n3;
       i += gridDim.x*blockDim.x) {
    const float4* src; unsigned short* dst; int off;
    if (i < n1)          { src = x;  dst = xb;  off = i; }
    else if (i < n1+n2)  { src = wq; dst = wqb; off = i - n1; }
    else                 { src = wo; dst = wob; off = i - n1 - n2; }
    float4 v = src[off];
    ushort4 r;
    r.x = f2bf(v.x); r.y = f2bf(v.y); r.z = f2bf(v.z); r.w = f2bf(v.w);
    *(ushort4*)&dst[off*4] = r;
  }
}

// ---------------------------------------------------------------------------
// GEMM C = A @ Bw^T.  3-buffer LDS pipeline, counted vmcnt (T3/T4):
//   iter t:  vmcnt(LPT) [tile t landed, t+1 in flight] ; s_barrier ;
//            STAGE(t+2) ; ds_read buf[t%3] ; MFMA.
// Never drains vmcnt to 0 in the main loop (m218: counted-vmcnt IS the gain;
// the old __syncthreads drain exposed full L2 latency every K-step).
// Race safety: STAGE(t+2) overwrites buf[(t-1)%3]; all waves consumed their
// (t-1) ds_reads before arriving at barrier t, and STAGE issues after it.
// BM x 128 tile, BK=32, 4 waves (2x2), wave tile (BM/2) x 64.
// EPI=0: store fp32 C.  EPI=1: scatter Q/K [B,H,S,DH] and Vt [B,H,DH,S] bf16.
// ---------------------------------------------------------------------------
template<int BM, int M, int N, int K, int EPI>
__global__ __launch_bounds__(256)
void gemm_bt(const unsigned short* __restrict__ A, const unsigned short* __restrict__ Bw,
             float* __restrict__ C, unsigned short* __restrict__ Qb,
             unsigned short* __restrict__ Kb, unsigned short* __restrict__ Vtb) {
  constexpr int NBN = N / 128;
  constexpr int MT  = BM / 32;     // M-frags per wave
  constexpr int AH  = BM / 64;     // A-stage gloads per thread
  constexpr int NSTEP = K / 32;
  __shared__ unsigned short As[3][BM*32];
  __shared__ unsigned short Bs[3][128*32];
  const int tid = threadIdx.x;
  const int bid = blockIdx.x;
  const int mb = bid / NBN, nb = bid % NBN;
  const int wid = tid >> 6, lane = tid & 63;
  const int wr = wid >> 1, wc = wid & 1;
  const int lg = lane >> 4, lr = lane & 15;

  f32x4 acc[MT][4] = {};

  const int mrow = mb*BM, nrow = nb*128;
  const int srow = tid >> 2;       // 0..63
  const int scol = (tid & 3) * 8;  // 0,8,16,24

  auto STAGE = [&](int t) {
    const int k0 = t*32, b = t % 3;
    #pragma unroll
    for (int h = 0; h < AH; ++h)
      gload_lds16(A  + (size_t)(mrow + h*64 + srow)*K + k0 + scol, &As[b][(h*256 + tid)*8]);
    #pragma unroll
    for (int h = 0; h < 2; ++h)
      gload_lds16(Bw + (size_t)(nrow + h*64 + srow)*K + k0 + scol, &Bs[b][(h*256 + tid)*8]);
  };

  STAGE(0);
  STAGE(1);
  for (int t = 0; t < NSTEP; ++t) {
    if (t < NSTEP-1) {
      if constexpr (AH == 1) asm volatile("s_waitcnt vmcnt(3)" ::: "memory");
      else                   asm volatile("s_waitcnt vmcnt(4)" ::: "memory");
    } else {
      asm volatile("s_waitcnt vmcnt(0)" ::: "memory");
    }
    __builtin_amdgcn_s_barrier();
    __builtin_amdgcn_sched_barrier(0);
    if (t + 2 < NSTEP) STAGE(t+2);
    const int b = t % 3;
    bf16x8 af[MT], bfr[4];
    #pragma unroll
    for (int m = 0; m < MT; ++m)
      af[m]  = *(const bf16x8*)&As[b][(wr*(BM/2) + m*16 + lr)*32 + lg*8];
    #pragma unroll
    for (int n = 0; n < 4; ++n)
      bfr[n] = *(const bf16x8*)&Bs[b][(wc*64 + n*16 + lr)*32 + lg*8];
    #pragma unroll
    for (int m = 0; m < MT; ++m)
      #pragma unroll
      for (int n = 0; n < 4; ++n)
        acc[m][n] = __builtin_amdgcn_mfma_f32_16x16x32_bf16(af[m], bfr[n], acc[m][n], 0, 0, 0);
  }

  // Epilogue. C/D layout: row = lg*4 + i, col = lr  (verified m89/m91).
  #pragma unroll
  for (int mt = 0; mt < MT; ++mt) {
    const int m0 = mrow + wr*(BM/2) + mt*16 + lg*4;
    #pragma unroll
    for (int nt = 0; nt < 4; ++nt) {
      const int n = nrow + wc*64 + nt*16 + lr;
      f32x4 v = acc[mt][nt];
      if constexpr (EPI == 0) {
        #pragma unroll
        for (int i = 0; i < 4; ++i) C[(size_t)(m0 + i)*N + n] = v[i];
      } else {
        const int t3 = n >> 10, rem = n & 1023;
        const int hh = rem >> 6, dh = rem & 63;
        const int b = m0 >> 10, s0 = m0 & 1023;
        if (t3 == 2) {
          ushort4 pk;
          pk.x = f2bf(v[0]); pk.y = f2bf(v[1]); pk.z = f2bf(v[2]); pk.w = f2bf(v[3]);
          *(ushort4*)&Vtb[(size_t)((b*H_ + hh)*DH_ + dh)*S_ + s0] = pk;
        } else {
          unsigned short* dst = (t3 == 0) ? Qb : Kb;
          #pragma unroll
          for (int i = 0; i < 4; ++i)
            dst[(size_t)((b*H_ + hh)*S_ + s0 + i)*DH_ + dh] = f2bf(v[i]);
        }
      }
    }
  }
}

// ---------------------------------------------------------------------------
// Flash attention v6 — 3-buffer counted-vmcnt pipeline (same scheme as GEMM).
// Grid: B*H*(S/64) = 512 blocks, 256 thr = 4 waves, wave owns 16 q-rows.
// LDS 57KB -> 2 blocks/CU. K/V staged via global_load_lds with pre-swizzled
// SOURCE chunks + swizzled reads (T2/#21). Swapped QK^T (mfma(K,Q)) ->
// in-lane softmax (16 keys/lane + 2 shfl). PV swapped accumulates O^T.
// XCD swizzle: bh = (rr>>4)*8 + bid%8 -> 4 heads/XCD (KV L2-resident).
// iter t: vmcnt(4)[tile t ready, t+1 in flight]; s_barrier; STAGE(t+2);
// compute buf[t%3]. No vmcnt(0) drain in the loop.
// ---------------------------------------------------------------------------
__global__ __launch_bounds__(256, 2)
void attn_kernel(const unsigned short* __restrict__ Qb, const unsigned short* __restrict__ Kb,
                 const unsigned short* __restrict__ Vtb, unsigned short* __restrict__ AOb) {
  __shared__ unsigned short Ks[3][64*64];
  __shared__ unsigned short Vs[3][64*64];
  __shared__ unsigned short Pl[4][16*72];
  const int bid = blockIdx.x;
  const int xcd = bid & 7, rr = bid >> 3;
  const int qt = rr & 15;                   // q-tile of 64 rows
  const int bh = (rr >> 4) * 8 + xcd;       // 0..31, XCD-local heads
  const int tid = threadIdx.x, wid = tid >> 6, lane = tid & 63;
  const int lg = lane >> 4, lr = lane & 15;
  const unsigned short* Q  = Qb  + (size_t)bh*S_*DH_;
  const unsigned short* Kp = Kb  + (size_t)bh*S_*DH_;
  const unsigned short* Vt = Vtb + (size_t)bh*DH_*S_;
  const int q0 = qt*64 + wid*16;

  // Q B-fragments (col=q=lr, k=lg*8+t), dh chunks 0 / 32
  bf16x8 qf0 = *(const bf16x8*)&Q[(size_t)(q0 + lr)*DH_ + lg*8];
  bf16x8 qf1 = *(const bf16x8*)&Q[(size_t)(q0 + lr)*DH_ + 32 + lg*8];

  // staging: 256 thr x 2 slots cover 64 rows x 8 chunks of 16B
  const int sr = tid >> 3;               // 0..31
  const int g0 = (tid & 7) ^ (sr & 7);   // pre-swizzled source chunk

  float mrun = -1e30f, lrun = 0.f;
  f32x4 o[4] = {};
  const int rsw = lr & 7;                // read-side swizzle key

  auto STAGE = [&](int t) {
    const int j = t * 64, b = t % 3;
    gload_lds16(Kp + (size_t)(j + sr)*DH_      + g0*8, &Ks[b][tid*8]);
    gload_lds16(Kp + (size_t)(j + sr + 32)*DH_ + g0*8, &Ks[b][(256+tid)*8]);
    gload_lds16(Vt + (size_t)sr*S_      + j + g0*8,    &Vs[b][tid*8]);
    gload_lds16(Vt + (size_t)(sr+32)*S_ + j + g0*8,    &Vs[b][(256+tid)*8]);
  };

  STAGE(0);
  STAGE(1);
  for (int t = 0; t < 16; ++t) {
    if (t < 15) asm volatile("s_waitcnt vmcnt(4)" ::: "memory");
    else        asm volatile("s_waitcnt vmcnt(0)" ::: "memory");
    __builtin_amdgcn_s_barrier();
    __builtin_amdgcn_sched_barrier(0);
    if (t + 2 < 16) STAGE(t+2);
    const int buf = t % 3;
    // QK^T swapped: sv[f] = S^T rows (keys) 16f+lg*4+i, col q=lr
    f32x4 sv[4];
    __builtin_amdgcn_s_setprio(1);
    #pragma unroll
    for (int f = 0; f < 4; ++f) {
      bf16x8 ka = *(const bf16x8*)&Ks[buf][(16*f + lr)*64 + ((lg     ^ rsw)*8)];
      bf16x8 kb = *(const bf16x8*)&Ks[buf][(16*f + lr)*64 + (((lg+4) ^ rsw)*8)];
      f32x4 z = {};
      z     = __builtin_amdgcn_mfma_f32_16x16x32_bf16(ka, qf0, z, 0, 0, 0);
      sv[f] = __builtin_amdgcn_mfma_f32_16x16x32_bf16(kb, qf1, z, 0, 0, 0);
    }
    __builtin_amdgcn_s_setprio(0);
    // in-lane softmax for q=lr over this lane's 16 keys
    float s[16];
    #pragma unroll
    for (int f = 0; f < 4; ++f)
      #pragma unroll
      for (int i = 0; i < 4; ++i) s[4*f + i] = sv[f][i] * 0.125f;
    float t8[8];
    #pragma unroll
    for (int k = 0; k < 8; ++k) t8[k] = fmaxf(s[k], s[k+8]);
    float t4a = fmaxf(t8[0], t8[4]), t4b = fmaxf(t8[1], t8[5]);
    float t4c = fmaxf(t8[2], t8[6]), t4d = fmaxf(t8[3], t8[7]);
    float pmax = fmaxf(fmaxf(t4a, t4b), fmaxf(t4c, t4d));
    pmax = fmaxf(pmax, __shfl_xor(pmax, 16));
    pmax = fmaxf(pmax, __shfl_xor(pmax, 32));
    float mnew = fmaxf(mrun, pmax);
    float cr = __expf(mrun - mnew);
    float p[16];
    #pragma unroll
    for (int k = 0; k < 16; ++k) p[k] = __expf(s[k] - mnew);
    float u8[8];
    #pragma unroll
    for (int k = 0; k < 8; ++k) u8[k] = p[k] + p[k+8];
    float u4a = u8[0]+u8[4], u4b = u8[1]+u8[5], u4c = u8[2]+u8[6], u4d = u8[3]+u8[7];
    float rs = (u4a + u4b) + (u4c + u4d);
    rs += __shfl_xor(rs, 16);
    rs += __shfl_xor(rs, 32);
    lrun = lrun*cr + rs;
    mrun = mnew;
    // P^T pack -> Pl[q=lr][key], 4x ds_write_b64 (keys 16f+lg*4 .. +3)
    #pragma unroll
    for (int f = 0; f < 4; ++f) {
      uint2 w;
      w.x = pack2bf(p[4*f],   p[4*f+1]);
      w.y = pack2bf(p[4*f+2], p[4*f+3]);
      *(uint2*)&Pl[wid][lr*72 + f*16 + lg*4] = w;
    }
    // rescale O^T by per-lane scalar
    #pragma unroll
    for (int dt = 0; dt < 4; ++dt) {
      o[dt][0] *= cr; o[dt][1] *= cr; o[dt][2] *= cr; o[dt][3] *= cr;
    }
    asm volatile("s_waitcnt lgkmcnt(0)" ::: "memory");
    __builtin_amdgcn_sched_barrier(0);
    // PV swapped: o[dt] += Vs[d][k] * P^T[k][q]
    __builtin_amdgcn_s_setprio(1);
    #pragma unroll
    for (int c = 0; c < 2; ++c) {
      bf16x8 pf = *(const bf16x8*)&Pl[wid][lr*72 + c*32 + lg*8];
      #pragma unroll
      for (int dt = 0; dt < 4; ++dt) {
        bf16x8 vfr = *(const bf16x8*)&Vs[buf][(dt*16 + lr)*64 + (((c*4 + lg) ^ rsw)*8)];
        o[dt] = __builtin_amdgcn_mfma_f32_16x16x32_bf16(vfr, pf, o[dt], 0, 0, 0);
      }
    }
    __builtin_amdgcn_s_setprio(0);
  }

  // epilogue: lane holds O^T[d = dt*16+lg*4+i][q = q0+lr]
  const float inv = 1.0f / lrun;
  const int b = bh >> 4, hh = bh & 15;
  #pragma unroll
  for (int dt = 0; dt < 4; ++dt) {
    ushort4 pk;
    pk.x = f2bf(o[dt][0]*inv); pk.y = f2bf(o[dt][1]*inv);
    pk.z = f2bf(o[dt][2]*inv); pk.w = f2bf(o[dt][3]*inv);
    *(ushort4*)&AOb[(size_t)(b*S_ + q0 + lr)*D_ + hh*DH_ + dt*16 + lg*4] = pk;
  }
}

// ---------------------------------------------------------------------------
extern "C" void kernel_launch(void* const* d_in, const int* in_sizes, int n_in,
                              void* d_out, int out_size, void* d_ws, size_t ws_size,
                              hipStream_t stream) {
  const float* x  = (const float*)d_in[0];   // [B,S,D]
  const float* wq = (const float*)d_in[1];   // [3D,D]
  const float* wo = (const float*)d_in[2];   // [D,D]
  float* out = (float*)d_out;                // [B,S,D] fp32

  unsigned short* w = (unsigned short*)d_ws;
  unsigned short* xb  = w;                   // 2097152 bf16
  unsigned short* wqb = xb  + 2097152;       // 3145728
  unsigned short* wob = wqb + 3145728;       // 1048576
  unsigned short* qb  = wob + 1048576;       // 2097152  Q [B,H,S,DH]
  unsigned short* kb  = qb  + 2097152;       // 2097152  K [B,H,S,DH]
  unsigned short* vtb = kb  + 2097152;       // 2097152  V^T [B,H,DH,S]
  unsigned short* aob = vtb + 2097152;       // 2097152  attn out [B,S,D]

  cvt_kernel<<<dim3(1024), dim3(256), 0, stream>>>(
      (const float4*)x, (const float4*)wq, (const float4*)wo, xb, wqb, wob);

  // QKV projection: M=2048, N=3072, K=1024 — BM=64 -> 768 blocks = 3/CU even
  gemm_bt<64, 2048, 3072, 1024, 1><<<dim3(32*24), dim3(256), 0, stream>>>(
      xb, wqb, nullptr, qb, kb, vtb);

  attn_kernel<<<dim3(512), dim3(256), 0, stream>>>(qb, kb, vtb, aob);

  // Output projection: M=2048, N=1024, K=1024 — BM=64 -> 256 blocks = 1/CU
  gemm_bt<64, 2048, 1024, 1024, 0><<<dim3(32*8), dim3(256), 0, stream>>>(
      aob, wob, out, nullptr, nullptr, nullptr);
}

// Round 8
// 135.513 us; speedup vs baseline: 1.3444x; 1.0355x over previous
//
#include <hip/hip_runtime.h>

// Problem dims (fixed)
#define B_  2
#define S_  1024
#define D_  1024
#define H_  16
#define DH_ 64

typedef __attribute__((ext_vector_type(8))) short bf16x8;
typedef __attribute__((ext_vector_type(4))) float f32x4;

__device__ __forceinline__ unsigned short f2bf(float f) {
  unsigned int u = __float_as_uint(f);
  u += 0x7fff + ((u >> 16) & 1);   // round-to-nearest-even
  return (unsigned short)(u >> 16);
}

__device__ __forceinline__ unsigned int pack2bf(float a, float b) {
  return (unsigned int)f2bf(a) | ((unsigned int)f2bf(b) << 16);
}

__device__ __forceinline__ void gload_lds16(const void* g, void* l) {
  __builtin_amdgcn_global_load_lds(
      (const __attribute__((address_space(1))) unsigned int*)g,
      (__attribute__((address_space(3))) unsigned int*)l, 16, 0, 0);
}

// ---------------------------------------------------------------------------
// Kernel 1: fp32 -> bf16 convert for x, W_qkv, W_out
// ---------------------------------------------------------------------------
__global__ __launch_bounds__(256)
void cvt_kernel(const float4* __restrict__ x, const float4* __restrict__ wq,
                const float4* __restrict__ wo, unsigned short* __restrict__ xb,
                unsigned short* __restrict__ wqb, unsigned short* __restrict__ wob) {
  constexpr int n1 = (B_*S_*D_) / 4;       // 524288
  constexpr int n2 = (3*D_*D_) / 4;        // 786432
  constexpr int n3 = (D_*D_) / 4;          // 262144
  for (int i = blockIdx.x*blockDim.x + threadIdx.x; i < n1+n2+n3;
       i += gridDim.x*blockDim.x) {
    const float4* src; unsigned short* dst; int off;
    if (i < n1)          { src = x;  dst = xb;  off = i; }
    else if (i < n1+n2)  { src = wq; dst = wqb; off = i - n1; }
    else                 { src = wo; dst = wob; off = i - n1 - n2; }
    float4 v = src[off];
    ushort4 r;
    r.x = f2bf(v.x); r.y = f2bf(v.y); r.z = f2bf(v.z); r.w = f2bf(v.w);
    *(ushort4*)&dst[off*4] = r;
  }
}

// ---------------------------------------------------------------------------
// Wave-autonomous GEMM: C = A @ Bw^T, A:[M,K] bf16, Bw:[N,K] bf16.
// Each WAVE owns a 64x64 tile with PRIVATE 3-buffer LDS (A,B 4KB each/buf).
// NO __syncthreads in the K-loop: wave self-paces on counted vmcnt(8)
// (tile t ready, t+1 in flight, stage(t+2) issued after reads of t). The
// barrier-lockstep drain of the 4-wave m97 structure (which R6/R7 showed is
// insensitive to scheduling) is gone entirely; co-resident waves interleave
// MFMA vs staging freely on the SIMDs.
// Bank math (64B rows, b128 reads): 8 lanes per 4-bank group = minimal.
// KHALF: wave wid covers K range [wid*K/2, ...) and partials are reduced
// through LDS once at the end (used by gemm2 to keep grid even at 2/CU).
// EPI=0: C += fp32 store (reduced).  EPI=1: scatter Q/K/Vt bf16.
// ---------------------------------------------------------------------------
template<int NTM, int NTN, int K, int EPI, int KHALF>
__global__ __launch_bounds__(128)
void gemm_wv(const unsigned short* __restrict__ A, const unsigned short* __restrict__ Bw,
             float* __restrict__ C, unsigned short* __restrict__ Qb,
             unsigned short* __restrict__ Kb, unsigned short* __restrict__ Vtb) {
  constexpr int KW    = KHALF ? K/2 : K;     // K range per wave
  constexpr int NSTEP = KW / 32;
  __shared__ unsigned short L[2][3][2][64*32];   // [wave][buf][A|B][tile] 48KB
  __shared__ float Ored[KHALF ? 64*64 : 1];      // gemm2 reduce buffer
  const int tid = threadIdx.x, wid = tid >> 6, lane = tid & 63;
  const int lg = lane >> 4, lr = lane & 15;

  // block -> tile mapping, XCD swizzle (grid % 8 == 0 in both uses)
  const int nblk = gridDim.x;
  const int sb = (blockIdx.x & 7) * (nblk >> 3) + (blockIdx.x >> 3);
  int mw, nw, kbase;
  if constexpr (KHALF) {           // 1 tile/block, wave = K-half
    mw = sb % NTM; nw = sb / NTM; kbase = wid * KW;
  } else {                         // 2 tiles/block (adjacent in M)
    const int wt = sb*2 + wid;
    mw = wt % NTM; nw = wt / NTM; kbase = 0;
  }
  const int m0 = mw*64, n0 = nw*64;
  const unsigned short* Ap = A  + kbase;
  const unsigned short* Bp = Bw + kbase;

  f32x4 acc[4][4] = {};

  auto STAGE = [&](int t) {
    const int k0 = t*32, b = t % 3;
    unsigned short* LA = &L[wid][b][0][0];
    unsigned short* LB = &L[wid][b][1][0];
    const int row = (lane >> 2), lc = lane & 3;
    #pragma unroll
    for (int g = 0; g < 4; ++g) {
      gload_lds16(Ap + (size_t)(m0 + g*16 + row)*K + k0 + lc*8, &LA[(g*64 + lane)*8]);
      gload_lds16(Bp + (size_t)(n0 + g*16 + row)*K + k0 + lc*8, &LB[(g*64 + lane)*8]);
    }
  };

  STAGE(0);
  STAGE(1);
  for (int t = 0; t < NSTEP; ++t) {
    if (t < NSTEP-1) asm volatile("s_waitcnt vmcnt(8)" ::: "memory");
    else             asm volatile("s_waitcnt vmcnt(0)" ::: "memory");
    __builtin_amdgcn_sched_barrier(0);
    const int b = t % 3;
    const unsigned short* LA = &L[wid][b][0][0];
    const unsigned short* LB = &L[wid][b][1][0];
    bf16x8 af[4], bf[4];
    #pragma unroll
    for (int m = 0; m < 4; ++m) af[m] = *(const bf16x8*)&LA[(m*16 + lr)*32 + lg*8];
    #pragma unroll
    for (int n = 0; n < 4; ++n) bf[n] = *(const bf16x8*)&LB[(n*16 + lr)*32 + lg*8];
    if (t + 2 < NSTEP) STAGE(t+2);   // overwrites buf[(t-1)%3], already consumed
    #pragma unroll
    for (int m = 0; m < 4; ++m)
      #pragma unroll
      for (int n = 0; n < 4; ++n)
        acc[m][n] = __builtin_amdgcn_mfma_f32_16x16x32_bf16(af[m], bf[n], acc[m][n], 0, 0, 0);
  }

  if constexpr (KHALF) {
    // reduce the two K-halves through LDS once, wave0 stores fp32 C
    if (wid == 1) {
      #pragma unroll
      for (int mt = 0; mt < 4; ++mt)
        #pragma unroll
        for (int nt = 0; nt < 4; ++nt)
          #pragma unroll
          for (int i = 0; i < 4; ++i)
            Ored[(mt*16 + lg*4 + i)*64 + nt*16 + lr] = acc[mt][nt][i];
    }
    __syncthreads();
    if (wid == 0) {
      #pragma unroll
      for (int mt = 0; mt < 4; ++mt)
        #pragma unroll
        for (int nt = 0; nt < 4; ++nt)
          #pragma unroll
          for (int i = 0; i < 4; ++i) {
            const int m = m0 + mt*16 + lg*4 + i, n = n0 + nt*16 + lr;
            C[(size_t)m*(NTN*64) + n] = acc[mt][nt][i] + Ored[(mt*16 + lg*4 + i)*64 + nt*16 + lr];
          }
    }
    return;
  }

  // EPI=1 epilogue: scatter to Q/K [B,H,S,DH] bf16, Vt [B,H,DH,S] bf16
  #pragma unroll
  for (int mt = 0; mt < 4; ++mt) {
    const int mm0 = m0 + mt*16 + lg*4;
    #pragma unroll
    for (int nt = 0; nt < 4; ++nt) {
      const int n = n0 + nt*16 + lr;
      f32x4 v = acc[mt][nt];
      const int t3 = n >> 10, rem = n & 1023;
      const int hh = rem >> 6, dh = rem & 63;
      const int b = mm0 >> 10, s0 = mm0 & 1023;
      if (t3 == 2) {
        ushort4 pk;
        pk.x = f2bf(v[0]); pk.y = f2bf(v[1]); pk.z = f2bf(v[2]); pk.w = f2bf(v[3]);
        *(ushort4*)&Vtb[(size_t)((b*H_ + hh)*DH_ + dh)*S_ + s0] = pk;
      } else {
        unsigned short* dst = (t3 == 0) ? Qb : Kb;
        #pragma unroll
        for (int i = 0; i < 4; ++i)
          dst[(size_t)((b*H_ + hh)*S_ + s0 + i)*DH_ + dh] = f2bf(v[i]);
      }
    }
  }
}

// ---------------------------------------------------------------------------
// Flash attention (R7 structure, unchanged): 3-buffer counted-vmcnt pipeline.
// Grid 512 blocks, 256 thr = 4 waves, wave owns 16 q-rows. K/V staged via
// global_load_lds with pre-swizzled source + swizzled reads. Swapped QK^T ->
// in-lane softmax. PV swapped accumulates O^T. XCD swizzle on heads.
// ---------------------------------------------------------------------------
__global__ __launch_bounds__(256, 2)
void attn_kernel(const unsigned short* __restrict__ Qb, const unsigned short* __restrict__ Kb,
                 const unsigned short* __restrict__ Vtb, unsigned short* __restrict__ AOb) {
  __shared__ unsigned short Ks[3][64*64];
  __shared__ unsigned short Vs[3][64*64];
  __shared__ unsigned short Pl[4][16*72];
  const int bid = blockIdx.x;
  const int xcd = bid & 7, rr = bid >> 3;
  const int qt = rr & 15;
  const int bh = (rr >> 4) * 8 + xcd;
  const int tid = threadIdx.x, wid = tid >> 6, lane = tid & 63;
  const int lg = lane >> 4, lr = lane & 15;
  const unsigned short* Q  = Qb  + (size_t)bh*S_*DH_;
  const unsigned short* Kp = Kb  + (size_t)bh*S_*DH_;
  const unsigned short* Vt = Vtb + (size_t)bh*DH_*S_;
  const int q0 = qt*64 + wid*16;

  bf16x8 qf0 = *(const bf16x8*)&Q[(size_t)(q0 + lr)*DH_ + lg*8];
  bf16x8 qf1 = *(const bf16x8*)&Q[(size_t)(q0 + lr)*DH_ + 32 + lg*8];

  const int sr = tid >> 3;               // 0..31
  const int g0 = (tid & 7) ^ (sr & 7);   // pre-swizzled source chunk

  float mrun = -1e30f, lrun = 0.f;
  f32x4 o[4] = {};
  const int rsw = lr & 7;

  auto STAGE = [&](int t) {
    const int j = t * 64, b = t % 3;
    gload_lds16(Kp + (size_t)(j + sr)*DH_      + g0*8, &Ks[b][tid*8]);
    gload_lds16(Kp + (size_t)(j + sr + 32)*DH_ + g0*8, &Ks[b][(256+tid)*8]);
    gload_lds16(Vt + (size_t)sr*S_      + j + g0*8,    &Vs[b][tid*8]);
    gload_lds16(Vt + (size_t)(sr+32)*S_ + j + g0*8,    &Vs[b][(256+tid)*8]);
  };

  STAGE(0);
  STAGE(1);
  for (int t = 0; t < 16; ++t) {
    if (t < 15) asm volatile("s_waitcnt vmcnt(4)" ::: "memory");
    else        asm volatile("s_waitcnt vmcnt(0)" ::: "memory");
    __builtin_amdgcn_s_barrier();
    __builtin_amdgcn_sched_barrier(0);
    if (t + 2 < 16) STAGE(t+2);
    const int buf = t % 3;
    f32x4 sv[4];
    __builtin_amdgcn_s_setprio(1);
    #pragma unroll
    for (int f = 0; f < 4; ++f) {
      bf16x8 ka = *(const bf16x8*)&Ks[buf][(16*f + lr)*64 + ((lg     ^ rsw)*8)];
      bf16x8 kb = *(const bf16x8*)&Ks[buf][(16*f + lr)*64 + (((lg+4) ^ rsw)*8)];
      f32x4 z = {};
      z     = __builtin_amdgcn_mfma_f32_16x16x32_bf16(ka, qf0, z, 0, 0, 0);
      sv[f] = __builtin_amdgcn_mfma_f32_16x16x32_bf16(kb, qf1, z, 0, 0, 0);
    }
    __builtin_amdgcn_s_setprio(0);
    float s[16];
    #pragma unroll
    for (int f = 0; f < 4; ++f)
      #pragma unroll
      for (int i = 0; i < 4; ++i) s[4*f + i] = sv[f][i] * 0.125f;
    float t8[8];
    #pragma unroll
    for (int k = 0; k < 8; ++k) t8[k] = fmaxf(s[k], s[k+8]);
    float t4a = fmaxf(t8[0], t8[4]), t4b = fmaxf(t8[1], t8[5]);
    float t4c = fmaxf(t8[2], t8[6]), t4d = fmaxf(t8[3], t8[7]);
    float pmax = fmaxf(fmaxf(t4a, t4b), fmaxf(t4c, t4d));
    pmax = fmaxf(pmax, __shfl_xor(pmax, 16));
    pmax = fmaxf(pmax, __shfl_xor(pmax, 32));
    float mnew = fmaxf(mrun, pmax);
    float cr = __expf(mrun - mnew);
    float p[16];
    #pragma unroll
    for (int k = 0; k < 16; ++k) p[k] = __expf(s[k] - mnew);
    float u8[8];
    #pragma unroll
    for (int k = 0; k < 8; ++k) u8[k] = p[k] + p[k+8];
    float u4a = u8[0]+u8[4], u4b = u8[1]+u8[5], u4c = u8[2]+u8[6], u4d = u8[3]+u8[7];
    float rs = (u4a + u4b) + (u4c + u4d);
    rs += __shfl_xor(rs, 16);
    rs += __shfl_xor(rs, 32);
    lrun = lrun*cr + rs;
    mrun = mnew;
    #pragma unroll
    for (int f = 0; f < 4; ++f) {
      uint2 w;
      w.x = pack2bf(p[4*f],   p[4*f+1]);
      w.y = pack2bf(p[4*f+2], p[4*f+3]);
      *(uint2*)&Pl[wid][lr*72 + f*16 + lg*4] = w;
    }
    #pragma unroll
    for (int dt = 0; dt < 4; ++dt) {
      o[dt][0] *= cr; o[dt][1] *= cr; o[dt][2] *= cr; o[dt][3] *= cr;
    }
    asm volatile("s_waitcnt lgkmcnt(0)" ::: "memory");
    __builtin_amdgcn_sched_barrier(0);
    __builtin_amdgcn_s_setprio(1);
    #pragma unroll
    for (int c = 0; c < 2; ++c) {
      bf16x8 pf = *(const bf16x8*)&Pl[wid][lr*72 + c*32 + lg*8];
      #pragma unroll
      for (int dt = 0; dt < 4; ++dt) {
        bf16x8 vfr = *(const bf16x8*)&Vs[buf][(dt*16 + lr)*64 + (((c*4 + lg) ^ rsw)*8)];
        o[dt] = __builtin_amdgcn_mfma_f32_16x16x32_bf16(vfr, pf, o[dt], 0, 0, 0);
      }
    }
    __builtin_amdgcn_s_setprio(0);
  }

  const float inv = 1.0f / lrun;
  const int b = bh >> 4, hh = bh & 15;
  #pragma unroll
  for (int dt = 0; dt < 4; ++dt) {
    ushort4 pk;
    pk.x = f2bf(o[dt][0]*inv); pk.y = f2bf(o[dt][1]*inv);
    pk.z = f2bf(o[dt][2]*inv); pk.w = f2bf(o[dt][3]*inv);
    *(ushort4*)&AOb[(size_t)(b*S_ + q0 + lr)*D_ + hh*DH_ + dt*16 + lg*4] = pk;
  }
}

// ---------------------------------------------------------------------------
extern "C" void kernel_launch(void* const* d_in, const int* in_sizes, int n_in,
                              void* d_out, int out_size, void* d_ws, size_t ws_size,
                              hipStream_t stream) {
  const float* x  = (const float*)d_in[0];   // [B,S,D]
  const float* wq = (const float*)d_in[1];   // [3D,D]
  const float* wo = (const float*)d_in[2];   // [D,D]
  float* out = (float*)d_out;                // [B,S,D] fp32

  unsigned short* w = (unsigned short*)d_ws;
  unsigned short* xb  = w;                   // 2097152 bf16
  unsigned short* wqb = xb  + 2097152;       // 3145728
  unsigned short* wob = wqb + 3145728;       // 1048576
  unsigned short* qb  = wob + 1048576;       // 2097152  Q [B,H,S,DH]
  unsigned short* kb  = qb  + 2097152;       // 2097152  K [B,H,S,DH]
  unsigned short* vtb = kb  + 2097152;       // 2097152  V^T [B,H,DH,S]
  unsigned short* aob = vtb + 2097152;       // 2097152  attn out [B,S,D]

  cvt_kernel<<<dim3(1024), dim3(256), 0, stream>>>(
      (const float4*)x, (const float4*)wq, (const float4*)wo, xb, wqb, wob);

  // QKV projection: M=2048, N=3072, K=1024. 32x48=1536 wave-tiles,
  // 2/block -> 768 blocks (3/CU even), column-major tile order for L2.
  gemm_wv<32, 48, 1024, 1, 0><<<dim3(768), dim3(128), 0, stream>>>(
      xb, wqb, nullptr, qb, kb, vtb);

  attn_kernel<<<dim3(512), dim3(256), 0, stream>>>(qb, kb, vtb, aob);

  // Output projection: M=2048, N=1024, K=1024. 32x16=512 tiles, 1/block
  // with K-split across the 2 waves -> 512 blocks (2/CU even).
  gemm_wv<32, 16, 1024, 0, 1><<<dim3(512), dim3(128), 0, stream>>>(
      aob, wob, out, nullptr, nullptr, nullptr);
}